// Round 6
// baseline (6100.503 us; speedup 1.0000x reference)
//
#include <hip/hip_runtime.h>
#include <math.h>

#define DEV __device__ __forceinline__

typedef _Float16 f16;
typedef _Float16 f16x8 __attribute__((ext_vector_type(8)));
typedef _Float16 f16x4 __attribute__((ext_vector_type(4)));
typedef float f32x4 __attribute__((ext_vector_type(4)));

DEV void gload_lds16(const void* g, void* l) {
  __builtin_amdgcn_global_load_lds(
      (const __attribute__((address_space(1))) void*)g,
      (__attribute__((address_space(3))) void*)l, 16, 0, 0);
}

// ---------------------------------------------------------------------------
// Weight transpose + f32->f16 convert: src [R][C] f32 -> dst [C][R] f16
// grid (C/32, R/32), block (32,8)
__global__ void transpose_w(const float* __restrict__ src, f16* __restrict__ dst,
                            int R, int C) {
  __shared__ float tile[32][33];
  int c0 = blockIdx.x * 32, r0 = blockIdx.y * 32;
  int tx = threadIdx.x, ty = threadIdx.y;
#pragma unroll
  for (int j = 0; j < 32; j += 8)
    tile[ty + j][tx] = src[(size_t)(r0 + ty + j) * C + c0 + tx];
  __syncthreads();
#pragma unroll
  for (int j = 0; j < 32; j += 8)
    dst[(size_t)(c0 + ty + j) * R + r0 + tx] = (f16)tile[tx][ty + j];
}

// ---------------------------------------------------------------------------
// RoPE sin/cos table: tab[pos][0..127]=sin, [128..255]=cos. 2048 pos x 128 j
__global__ void rope_table_k(float* __restrict__ tab) {
  int idx = blockIdx.x * 256 + threadIdx.x;  // 1024 blocks -> 262144 = 2048*128
  int pos = idx >> 7, j = idx & 127;
  float ts = powf(10000.0f, (float)j * (1.0f / 128.0f));
  float ang = (float)pos / ts;
  tab[pos * 256 + j] = sinf(ang);
  tab[pos * 256 + 128 + j] = cosf(ang);
}

// ---------------------------------------------------------------------------
// h = rmsnorm(in, scale) -> f16. one block per row, D=2560
__global__ __launch_bounds__(256) void rmsnorm_f32_f16(
    const float* __restrict__ in, const float* __restrict__ scale,
    f16* __restrict__ out) {
  constexpr int D = 2560, N4 = D / 4;
  const int m = blockIdx.x, tid = threadIdx.x;
  const float* row = in + (size_t)m * D;
  float vals[12];
  float ss = 0.f;
#pragma unroll
  for (int it = 0; it < 3; ++it) {
    int c4 = tid + it * 256;
    if (c4 < N4) {
      float4 v = *(const float4*)(row + c4 * 4);
      vals[it * 4 + 0] = v.x; vals[it * 4 + 1] = v.y;
      vals[it * 4 + 2] = v.z; vals[it * 4 + 3] = v.w;
      ss += v.x * v.x + v.y * v.y + v.z * v.z + v.w * v.w;
    }
  }
#pragma unroll
  for (int off = 32; off; off >>= 1) ss += __shfl_xor(ss, off, 64);
  __shared__ float red[4];
  if ((tid & 63) == 0) red[tid >> 6] = ss;
  __syncthreads();
  float rs = rsqrtf((red[0] + red[1] + red[2] + red[3]) * (1.0f / D) + 1e-6f);
#pragma unroll
  for (int it = 0; it < 3; ++it) {
    int c4 = tid + it * 256;
    if (c4 < N4) {
      float4 sc = *(const float4*)(scale + c4 * 4);
      f16x4 o;
      o[0] = (f16)(vals[it * 4 + 0] * rs * sc.x);
      o[1] = (f16)(vals[it * 4 + 1] * rs * sc.y);
      o[2] = (f16)(vals[it * 4 + 2] * rs * sc.z);
      o[3] = (f16)(vals[it * 4 + 3] * rs * sc.w);
      *(f16x4*)(out + (size_t)m * D + c4 * 4) = o;
    }
  }
}

// out = x + rmsnorm(y, scale); safe when out aliases x (per-thread RMW)
__global__ __launch_bounds__(256) void residual_rmsnorm(
    const float* x, const f16* __restrict__ y,
    const float* __restrict__ scale, float* out) {
  constexpr int D = 2560, N4 = D / 4;
  const int m = blockIdx.x, tid = threadIdx.x;
  const f16* yr = y + (size_t)m * D;
  float yv[12];
  float ss = 0.f;
#pragma unroll
  for (int it = 0; it < 3; ++it) {
    int c4 = tid + it * 256;
    if (c4 < N4) {
      f16x4 u = *(const f16x4*)(yr + c4 * 4);
      float a = (float)u[0], b = (float)u[1], c = (float)u[2], d = (float)u[3];
      yv[it * 4 + 0] = a; yv[it * 4 + 1] = b; yv[it * 4 + 2] = c; yv[it * 4 + 3] = d;
      ss += a * a + b * b + c * c + d * d;
    }
  }
#pragma unroll
  for (int off = 32; off; off >>= 1) ss += __shfl_xor(ss, off, 64);
  __shared__ float red[4];
  if ((tid & 63) == 0) red[tid >> 6] = ss;
  __syncthreads();
  float rs = rsqrtf((red[0] + red[1] + red[2] + red[3]) * (1.0f / D) + 1e-6f);
#pragma unroll
  for (int it = 0; it < 3; ++it) {
    int c4 = tid + it * 256;
    if (c4 < N4) {
      float4 xv = *(const float4*)(x + (size_t)m * D + c4 * 4);
      float4 sc = *(const float4*)(scale + c4 * 4);
      float4 o;
      o.x = xv.x + yv[it * 4 + 0] * rs * sc.x;
      o.y = xv.y + yv[it * 4 + 1] * rs * sc.y;
      o.z = xv.z + yv[it * 4 + 2] * rs * sc.z;
      o.w = xv.w + yv[it * 4 + 3] * rs * sc.w;
      *(float4*)(out + (size_t)m * D + c4 * 4) = o;
    }
  }
}

// ---------------------------------------------------------------------------
// Per-head rmsnorm (+RoPE for q,k) on qkv [4096][4096] f16.
// vectors: 0-7 q heads, 8-11 k heads, 12-15 v heads. one block per token.
__global__ __launch_bounds__(256) void norm_rope_k(
    const f16* __restrict__ qkv, const int* __restrict__ positions,
    const float* __restrict__ q_scale, const float* __restrict__ k_scale,
    const float* __restrict__ tab,
    f16* __restrict__ q_g, f16* __restrict__ k_g, f16* __restrict__ v_n) {
  const int m = blockIdx.x;
  const int tid = threadIdx.x, w = tid >> 6, l = tid & 63;
  const int pos = positions[m];
  const float* srow = tab + (size_t)pos * 256;
  const int c0 = l * 4;
  for (int vi = w; vi < 16; vi += 4) {
    f16x4 u = *(const f16x4*)(qkv + (size_t)m * 4096 + vi * 256 + c0);
    float x0 = (float)u[0], x1 = (float)u[1], x2 = (float)u[2], x3 = (float)u[3];
    float ss = x0 * x0 + x1 * x1 + x2 * x2 + x3 * x3;
#pragma unroll
    for (int off = 32; off; off >>= 1) ss += __shfl_xor(ss, off, 64);
    float rs = rsqrtf(ss * (1.0f / 256.0f) + 1e-6f);
    if (vi < 12) {
      const float* sc = (vi < 8) ? q_scale : k_scale;
      float4 s4 = *(const float4*)(sc + c0);
      float n0 = x0 * rs * s4.x, n1 = x1 * rs * s4.y;
      float n2 = x2 * rs * s4.z, n3 = x3 * rs * s4.w;
      float p0 = __shfl_xor(n0, 32, 64), p1 = __shfl_xor(n1, 32, 64);
      float p2 = __shfl_xor(n2, 32, 64), p3 = __shfl_xor(n3, 32, 64);
      int j0 = c0 & 127;
      float4 sn = *(const float4*)(srow + j0);
      float4 cs = *(const float4*)(srow + 128 + j0);
      float sgn = (l < 32) ? -1.0f : 1.0f;
      f16x4 o;
      o[0] = (f16)(n0 * cs.x + sgn * p0 * sn.x);
      o[1] = (f16)(n1 * cs.y + sgn * p1 * sn.y);
      o[2] = (f16)(n2 * cs.z + sgn * p2 * sn.z);
      o[3] = (f16)(n3 * cs.w + sgn * p3 * sn.w);
      if (vi < 8) *(f16x4*)(q_g + (size_t)m * 2048 + vi * 256 + c0) = o;
      else        *(f16x4*)(k_g + (size_t)m * 1024 + (vi - 8) * 256 + c0) = o;
    } else {
      f16x4 o;
      o[0] = (f16)(x0 * rs); o[1] = (f16)(x1 * rs);
      o[2] = (f16)(x2 * rs); o[3] = (f16)(x3 * rs);
      *(f16x4*)(v_n + (size_t)m * 1024 + (vi - 12) * 256 + c0) = o;
    }
  }
}

// v_n [4096][1024] -> vt [B*KV=8][256][2048] (per-(b,kv) transposed)
__global__ void transpose_v_k(const f16* __restrict__ v_n, f16* __restrict__ vt) {
  __shared__ f16 tile[32][33];
  int bkv = blockIdx.z;
  int b = bkv >> 2, kv = bkv & 3;
  int t0 = blockIdx.x * 32, d0 = blockIdx.y * 32;
  int tx = threadIdx.x, ty = threadIdx.y;
#pragma unroll
  for (int j = 0; j < 32; j += 8)
    tile[ty + j][tx] =
        v_n[(size_t)(b * 2048 + t0 + ty + j) * 1024 + kv * 256 + d0 + tx];
  __syncthreads();
#pragma unroll
  for (int j = 0; j < 32; j += 8)
    vt[((size_t)bkv * 256 + d0 + ty + j) * 2048 + t0 + tx] = tile[tx][ty + j];
}

// ---------------------------------------------------------------------------
// 256x256 GEMM, round-2/4 schedule: 2 barriers per K-tile, counted
// vmcnt(6)/(4)/(0). BK=64, 128KB LDS double-buffer, 1 block/CU.
// Round-locality decode: bm = orig & 15, bn = orig >> 4 (M==4096 required).
// EPI: 0=store, 1=gelu(exact), 2=mul by aux[idx] (in-place allowed).
template <int EPI>
__global__ __launch_bounds__(512, 2) void gemm256(
    const f16* __restrict__ A, const f16* __restrict__ BT,
    f16* __restrict__ C, const f16* __restrict__ aux, int M, int N, int K) {
  extern __shared__ __align__(16) f16 lds[];  // 131072 B
  const int tid = threadIdx.x;
  const int w = tid >> 6, l = tid & 63;
  const int l15 = l & 15, lk = l >> 4;
  const int wm = w >> 2, wn = w & 3;  // 2 x 4 wave grid

  // round-locality decode (see header comment)
  const int orig = blockIdx.y * gridDim.x + blockIdx.x;
  const int bm = orig & 15;
  const int bn = orig >> 4;

  const int NT = K >> 6;

  // staging: thread writes 16B chunks at panel rows srow, srow+128.
  // source col pre-swizzled so linear global_load_lds + swizzled ds_read agree.
  const int srow = tid >> 2;
  const int sg = (tid & 3) ^ ((srow >> 1) & 3);
  const f16* pA1 = A + (size_t)(bm * 256 + srow) * K + sg * 8;
  const f16* pA2 = pA1 + (size_t)128 * K;
  const f16* pB1 = BT + (size_t)(bn * 256 + srow) * K + sg * 8;
  const f16* pB2 = pB1 + (size_t)128 * K;

  auto stage = [&](int op, int kh, int buf, int kt) {
    const int kb = kt * 64 + kh * 32;
    const f16* s1 = (op ? pB1 : pA1) + kb;
    const f16* s2 = (op ? pB2 : pA2) + kb;
    f16* dst = lds + ((buf << 2) + (kh << 1) + op) * 8192 + tid * 8;
    gload_lds16(s1, dst);
    gload_lds16(s2, dst + 4096);
  };

  // frag read offsets: row*32 elts + swizzled 16B slot (constant per thread)
  const int fcol = (lk ^ ((l15 >> 1) & 3)) << 3;
  const int aoff = (wm * 128 + l15) * 32 + fcol;          // A unit base + mi*512
  const int boff = 8192 + (wn * 64 + l15) * 32 + fcol;    // B unit base + ni*512

  f32x4 acc[8][4] = {};

  // prologue: A0(0), B0(0), A1(0), B1(0), A0(1). vmcnt(6) -> first 2 units landed.
  stage(0, 0, 0, 0);
  stage(1, 0, 0, 0);
  stage(0, 1, 0, 0);
  stage(1, 1, 0, 0);
  if (NT > 1) stage(0, 0, 1, 1);
  asm volatile("s_waitcnt vmcnt(6)" ::: "memory");
  __builtin_amdgcn_s_barrier();
  asm volatile("" ::: "memory");

  for (int t = 0; t < NT; ++t) {
    const int buf = t & 1, nbuf = buf ^ 1;
    const f16* lb0 = lds + buf * 32768;   // kh0 units
    const f16* lb1 = lb0 + 16384;         // kh1 units
    {
      // ---- pair 1: kh0 (A lo+hi, B; 32 MFMA) ----
      f16x8 a1[4], b[4], a2[4];
#pragma unroll
      for (int i = 0; i < 4; ++i) a1[i] = *(const f16x8*)(lb0 + aoff + i * 512);
#pragma unroll
      for (int i = 0; i < 4; ++i) b[i] = *(const f16x8*)(lb0 + boff + i * 512);
#pragma unroll
      for (int i = 0; i < 4; ++i) a2[i] = *(const f16x8*)(lb0 + aoff + (4 + i) * 512);
      if (t + 1 < NT) stage(1, 0, nbuf, t + 1);
      __builtin_amdgcn_s_setprio(1);
#pragma unroll
      for (int mi = 0; mi < 4; ++mi)
#pragma unroll
        for (int ni = 0; ni < 4; ++ni)
          acc[mi][ni] = __builtin_amdgcn_mfma_f32_16x16x32_f16(a1[mi], b[ni], acc[mi][ni], 0, 0, 0);
      __builtin_amdgcn_s_setprio(0);
      if (t + 1 < NT) stage(0, 1, nbuf, t + 1);
      __builtin_amdgcn_s_setprio(1);
#pragma unroll
      for (int mi = 0; mi < 4; ++mi)
#pragma unroll
        for (int ni = 0; ni < 4; ++ni)
          acc[4 + mi][ni] = __builtin_amdgcn_mfma_f32_16x16x32_f16(a2[mi], b[ni], acc[4 + mi][ni], 0, 0, 0);
      __builtin_amdgcn_s_setprio(0);
    }
    // guard: A1(t),B1(t) staged for pair 2 (exact count at tail)
    if (t + 1 < NT) asm volatile("s_waitcnt vmcnt(6)" ::: "memory");
    else            asm volatile("s_waitcnt vmcnt(0)" ::: "memory");
    __builtin_amdgcn_s_barrier();
    asm volatile("" ::: "memory");
    {
      // ---- pair 2: kh1 ----
      f16x8 a1[4], b[4], a2[4];
#pragma unroll
      for (int i = 0; i < 4; ++i) a1[i] = *(const f16x8*)(lb1 + aoff + i * 512);
#pragma unroll
      for (int i = 0; i < 4; ++i) b[i] = *(const f16x8*)(lb1 + boff + i * 512);
#pragma unroll
      for (int i = 0; i < 4; ++i) a2[i] = *(const f16x8*)(lb1 + aoff + (4 + i) * 512);
      if (t + 1 < NT) stage(1, 1, nbuf, t + 1);
      __builtin_amdgcn_s_setprio(1);
#pragma unroll
      for (int mi = 0; mi < 4; ++mi)
#pragma unroll
        for (int ni = 0; ni < 4; ++ni)
          acc[mi][ni] = __builtin_amdgcn_mfma_f32_16x16x32_f16(a1[mi], b[ni], acc[mi][ni], 0, 0, 0);
      __builtin_amdgcn_s_setprio(0);
      if (t + 2 < NT) stage(0, 0, buf, t + 2);  // A-kh0(t) dead since pair-1 reads
      __builtin_amdgcn_s_setprio(1);
#pragma unroll
      for (int mi = 0; mi < 4; ++mi)
#pragma unroll
        for (int ni = 0; ni < 4; ++ni)
          acc[4 + mi][ni] = __builtin_amdgcn_mfma_f32_16x16x32_f16(a2[mi], b[ni], acc[4 + mi][ni], 0, 0, 0);
      __builtin_amdgcn_s_setprio(0);
    }
    // guard: A0(t+1),B0(t+1) staged for next pair-1 (exact count at tail)
    if (t + 2 < NT)      asm volatile("s_waitcnt vmcnt(6)" ::: "memory");
    else if (t + 1 < NT) asm volatile("s_waitcnt vmcnt(4)" ::: "memory");
    else                 asm volatile("s_waitcnt vmcnt(0)" ::: "memory");
    __builtin_amdgcn_s_barrier();
    asm volatile("" ::: "memory");
  }

  // epilogue: C/D map col=l15, row=lk*4+i (m89-verified)
#pragma unroll
  for (int mi = 0; mi < 8; ++mi) {
#pragma unroll
    for (int ni = 0; ni < 4; ++ni) {
#pragma unroll
      for (int i = 0; i < 4; ++i) {
        int row = bm * 256 + wm * 128 + mi * 16 + lk * 4 + i;
        int col = bn * 256 + wn * 64 + ni * 16 + l15;
        size_t idx = (size_t)row * N + col;
        float v = acc[mi][ni][i];
        if constexpr (EPI == 1) {
          v = 0.5f * v * (1.0f + erff(v * 0.70710678118654752f));
        } else if constexpr (EPI == 2) {
          v *= (float)aux[idx];
        }
        C[idx] = (f16)v;
      }
    }
  }
}

// ---------------------------------------------------------------------------
// Fused gate+up GEMM, BK=32, 64KB LDS -> 2 blocks/CU (cross-block TLP covers
// barrier/lgkm stalls; m114 mechanism). 512 threads = 8 waves (2Mx4N).
// B-panel: rows 0-127 = gate^T slice, rows 128-255 = up^T slice (128 cols of
// C per block). Per K-tile: 12 ds_reads -> stage next tile into opposite
// buffer (4 gloads, covered by 32 MFMA before the vmcnt(0)) -> 32 MFMA ->
// vmcnt(0); barrier. Same XOR swizzle as gemm256 (units are [256][32] f16).
// Epilogue: two-pass gelu(gate) exchange via [128][136] f16 LDS (34.8 KB).
// grid: (N/128, 16); decode bm = orig & 15, bn = orig >> 4. M==4096, K%32==0.
__global__ __launch_bounds__(512, 4) void gemm_fused32(
    const f16* __restrict__ A, const f16* __restrict__ GT,
    f16* __restrict__ C, const f16* __restrict__ UT, int M, int N, int K) {
  extern __shared__ __align__(16) f16 lds[];  // 65536 B
  const int tid = threadIdx.x;
  const int w = tid >> 6, l = tid & 63;
  const int l15 = l & 15, lk = l >> 4;
  const int wm = w >> 2, wn = w & 3;

  const int orig = blockIdx.y * gridDim.x + blockIdx.x;
  const int bm = orig & 15;
  const int bn = orig >> 4;

  const int NT = K >> 5;

  const int srow = tid >> 2;
  const int sg = (tid & 3) ^ ((srow >> 1) & 3);
  const f16* pA1 = A + (size_t)(bm * 256 + srow) * K + sg * 8;
  const f16* pA2 = pA1 + (size_t)128 * K;
  const f16* pB1 = GT + (size_t)(bn * 128 + srow) * K + sg * 8;  // B rows 0-127
  const f16* pB2 = UT + (size_t)(bn * 128 + srow) * K + sg * 8;  // B rows 128-255

  // unit = [256 rows][32 k] f16 = 16KB; lds[(buf*2 + op) * 8192]
  auto stage = [&](int op, int buf, int kt) {
    const f16* s1 = (op ? pB1 : pA1) + kt * 32;
    const f16* s2 = (op ? pB2 : pA2) + kt * 32;
    f16* dst = lds + ((buf << 1) + op) * 8192 + tid * 8;
    gload_lds16(s1, dst);
    gload_lds16(s2, dst + 4096);
  };

  const int fcol = (lk ^ ((l15 >> 1) & 3)) << 3;
  const int aoff = (wm * 128 + l15) * 32 + fcol;  // + mi*512
  const int boff = 8192 + ((wn >> 1) * 128 + (wn & 1) * 64 + l15) * 32 + fcol;  // + ni*512

  f32x4 acc[8][4] = {};

  stage(0, 0, 0);
  stage(1, 0, 0);
  asm volatile("s_waitcnt vmcnt(0)" ::: "memory");
  __builtin_amdgcn_s_barrier();
  asm volatile("" ::: "memory");

  for (int t = 0; t < NT; ++t) {
    const int buf = t & 1;
    const f16* lb = lds + buf * 16384;
    f16x8 a[8], b[4];
#pragma unroll
    for (int i = 0; i < 8; ++i) a[i] = *(const f16x8*)(lb + aoff + i * 512);
#pragma unroll
    for (int i = 0; i < 4; ++i) b[i] = *(const f16x8*)(lb + boff + i * 512);
    if (t + 1 < NT) {
      stage(0, buf ^ 1, t + 1);
      stage(1, buf ^ 1, t + 1);
    }
    __builtin_amdgcn_s_setprio(1);
#pragma unroll
    for (int mi = 0; mi < 8; ++mi)
#pragma unroll
      for (int ni = 0; ni < 4; ++ni)
        acc[mi][ni] = __builtin_amdgcn_mfma_f32_16x16x32_f16(a[mi], b[ni], acc[mi][ni], 0, 0, 0);
    __builtin_amdgcn_s_setprio(0);
    asm volatile("s_waitcnt vmcnt(0)" ::: "memory");
    __builtin_amdgcn_s_barrier();
    asm volatile("" ::: "memory");
  }

  // two-pass gelu(gate) exchange: wm-half h writes rows h*128..h*128+127
  constexpr int XP = 136;  // 272B row stride -> <=2-way bank aliasing
  f16* xls = lds;          // [128][136] f16 = 34.8 KB
#pragma unroll
  for (int half = 0; half < 2; ++half) {
    __syncthreads();
    if (wm == half && wn < 2) {
#pragma unroll
      for (int mi = 0; mi < 8; ++mi)
#pragma unroll
        for (int ni = 0; ni < 4; ++ni)
#pragma unroll
          for (int i = 0; i < 4; ++i) {
            int row = mi * 16 + lk * 4 + i;
            int col = wn * 64 + ni * 16 + l15;
            float v = acc[mi][ni][i];
            v = 0.5f * v * (1.0f + erff(v * 0.70710678118654752f));
            xls[row * XP + col] = (f16)v;
          }
    }
    __syncthreads();
    if (wm == half && wn >= 2) {
#pragma unroll
      for (int mi = 0; mi < 8; ++mi)
#pragma unroll
        for (int ni = 0; ni < 4; ++ni)
#pragma unroll
          for (int i = 0; i < 4; ++i) {
            int row = mi * 16 + lk * 4 + i;
            int colg = (wn - 2) * 64 + ni * 16 + l15;
            float g = (float)xls[row * XP + colg];
            float v = g * acc[mi][ni][i];
            C[(size_t)(bm * 256 + half * 128 + row) * N + bn * 128 + colg] = (f16)v;
          }
    }
  }
}

// ---------------------------------------------------------------------------
// Flash attention, sliding window 1024, GQA rep=2.
// grid (L/64, H, B), block 256 (4 waves, 16 q-rows each). KV tile = 32.
__global__ __launch_bounds__(256) void flash_attn_k(
    const f16* __restrict__ q_g, const f16* __restrict__ k_g,
    const f16* __restrict__ vt, f16* __restrict__ ctx) {
  constexpr int KP = 264, VP = 40, PP = 40;
  __shared__ f16 Ks[32 * KP];
  __shared__ f16 Vs[256 * VP];
  __shared__ f16 Ps[4][16 * PP];
  const int qt = blockIdx.x, h = blockIdx.y, b = blockIdx.z;
  const int tid = threadIdx.x, w = tid >> 6, l = tid & 63;
  const int l15 = l & 15, lk = l >> 4;
  const int kv = h >> 1;

  f16x8 aq[8];
  const int qrow = qt * 64 + w * 16 + l15;
  const f16* qp = q_g + (size_t)(b * 2048 + qrow) * 2048 + h * 256 + lk * 8;
#pragma unroll
  for (int kc = 0; kc < 8; ++kc) aq[kc] = *(const f16x8*)(qp + kc * 32);

  f32x4 o[16] = {};
  float mrow[4] = {-1e30f, -1e30f, -1e30f, -1e30f};
  float lrow[4] = {0.f, 0.f, 0.f, 0.f};

  int kt_lo = 2 * qt - 32; if (kt_lo < 0) kt_lo = 0;
  const int kt_hi = 2 * qt + 1;
  const int iqb = qt * 64 + w * 16 + lk * 4;

  for (int kt = kt_lo; kt <= kt_hi; ++kt) {
    __syncthreads();
#pragma unroll
    for (int it = 0; it < 4; ++it) {
      int ch = tid + it * 256;
      int jl = ch >> 5, kcc = (ch & 31) * 8;
      *(f16x8*)&Ks[jl * KP + kcc] = *(const f16x8*)(
          k_g + (size_t)(b * 2048 + kt * 32 + jl) * 1024 + kv * 256 + kcc);
      int d = ch >> 2, tc = (ch & 3) * 8;
      *(f16x8*)&Vs[d * VP + tc] = *(const f16x8*)(
          vt + ((size_t)(b * 4 + kv) * 256 + d) * 2048 + kt * 32 + tc);
    }
    __syncthreads();
    // S = Q K^T  (16q x 32k per wave)
    f32x4 s[2] = {};
#pragma unroll
    for (int ct = 0; ct < 2; ++ct)
#pragma unroll
      for (int kc = 0; kc < 8; ++kc) {
        f16x8 bk = *(const f16x8*)&Ks[(ct * 16 + l15) * KP + kc * 32 + lk * 8];
        s[ct] = __builtin_amdgcn_mfma_f32_16x16x32_f16(aq[kc], bk, s[ct], 0, 0, 0);
      }
    // mask + online softmax
    float pm[4] = {-1e30f, -1e30f, -1e30f, -1e30f};
#pragma unroll
    for (int ct = 0; ct < 2; ++ct)
#pragma unroll
      for (int i = 0; i < 4; ++i) {
        int iq = iqb + i;
        int j = kt * 32 + ct * 16 + l15;
        bool valid = (j <= iq) && (j > iq - 1024);
        float sv = valid ? s[ct][i] : -1e30f;
        s[ct][i] = sv;
        pm[i] = fmaxf(pm[i], sv);
      }
#pragma unroll
    for (int i = 0; i < 4; ++i)
#pragma unroll
      for (int off = 1; off < 16; off <<= 1)
        pm[i] = fmaxf(pm[i], __shfl_xor(pm[i], off, 64));
    float corr[4], rsum[4];
#pragma unroll
    for (int i = 0; i < 4; ++i) {
      float mn = fmaxf(mrow[i], pm[i]);
      corr[i] = __expf(mrow[i] - mn);
      mrow[i] = mn;
      rsum[i] = 0.f;
    }
#pragma unroll
    for (int ct = 0; ct < 2; ++ct)
#pragma unroll
      for (int i = 0; i < 4; ++i) {
        float p = (s[ct][i] > -1e29f) ? __expf(s[ct][i] - mrow[i]) : 0.f;
        s[ct][i] = p;
        rsum[i] += p;
      }
#pragma unroll
    for (int i = 0; i < 4; ++i) {
#pragma unroll
      for (int off = 1; off < 16; off <<= 1) rsum[i] += __shfl_xor(rsum[i], off, 64);
      lrow[i] = lrow[i] * corr[i] + rsum[i];
    }
#pragma unroll
    for (int dt = 0; dt < 16; ++dt)
#pragma unroll
      for (int i = 0; i < 4; ++i) o[dt][i] *= corr[i];
    // P -> LDS (f16)
#pragma unroll
    for (int ct = 0; ct < 2; ++ct)
#pragma unroll
      for (int i = 0; i < 4; ++i)
        Ps[w][(lk * 4 + i) * PP + ct * 16 + l15] = (f16)s[ct][i];
    __syncthreads();
    // O += P V
    f16x8 pa = *(const f16x8*)&Ps[w][l15 * PP + lk * 8];
#pragma unroll
    for (int dt = 0; dt < 16; ++dt) {
      f16x8 bv = *(const f16x8*)&Vs[(dt * 16 + l15) * VP + lk * 8];
      o[dt] = __builtin_amdgcn_mfma_f32_16x16x32_f16(pa, bv, o[dt], 0, 0, 0);
    }
  }
  float inv[4];
#pragma unroll
  for (int i = 0; i < 4; ++i) inv[i] = 1.0f / lrow[i];
  f16* op = ctx + (size_t)(b * 2048 + qt * 64 + w * 16 + lk * 4) * 2048 + h * 256 + l15;
#pragma unroll
  for (int dt = 0; dt < 16; ++dt)
#pragma unroll
    for (int i = 0; i < 4; ++i)
      op[(size_t)i * 2048 + dt * 16] = (f16)(o[dt][i] * inv[i]);
}

// ---------------------------------------------------------------------------
extern "C" void kernel_launch(void* const* d_in, const int* in_sizes, int n_in,
                              void* d_out, int out_size, void* d_ws, size_t ws_size,
                              hipStream_t stream) {
  const float* x = (const float*)d_in[0];
  const int* positions = (const int*)d_in[1];
  const float* wq = (const float*)d_in[2];
  const float* wk = (const float*)d_in[3];
  const float* wv = (const float*)d_in[4];
  const float* wo = (const float*)d_in[5];
  const float* q_scale = (const float*)d_in[6];
  const float* k_scale = (const float*)d_in[7];
  const float* pre_attn = (const float*)d_in[8];
  const float* post_attn = (const float*)d_in[9];
  const float* pre_ffw = (const float*)d_in[10];
  const float* post_ffw = (const float*)d_in[11];
  const float* w_gate = (const float*)d_in[12];
  const float* w_up = (const float*)d_in[13];
  const float* w_down = (const float*)d_in[14];
  float* out = (float*)d_out;

  // one-time: allow large dynamic LDS (attribute set, not a stream op)
  static bool s_attr = []() {
    hipFuncSetAttribute(reinterpret_cast<const void*>(&gemm256<0>),
                        hipFuncAttributeMaxDynamicSharedMemorySize, 131072);
    hipFuncSetAttribute(reinterpret_cast<const void*>(&gemm256<1>),
                        hipFuncAttributeMaxDynamicSharedMemorySize, 131072);
    hipFuncSetAttribute(reinterpret_cast<const void*>(&gemm256<2>),
                        hipFuncAttributeMaxDynamicSharedMemorySize, 131072);
    hipFuncSetAttribute(reinterpret_cast<const void*>(&gemm_fused32),
                        hipFuncAttributeMaxDynamicSharedMemorySize, 65536);
    return true;
  }();
  (void)s_attr;

  // ---- workspace layout ----
  const size_t WT_BIG   = (size_t)20480 * 2560 * 2;  // gate^T + up^T resident
  const size_t WT_SMALL = (size_t)10240 * 2560 * 2;
  const size_t TAB_B = (size_t)2048 * 256 * 4;
  const size_t H_B   = (size_t)4096 * 2560 * 2;
  const size_t ACT_B = (size_t)92280832;
  auto aln = [](size_t v) { return (v + 255) & ~(size_t)255; };
  const bool big = ws_size >= aln(WT_BIG) + aln(TAB_B) + aln(H_B) + aln(ACT_B);

  char* ws = (char*)d_ws;
  size_t off = 0;
  auto alloc = [&](size_t bytes) {
    char* p = ws + off;
    off += (bytes + 255) & ~(size_t)255;
    return p;
  };
  f16* wT    = (f16*)alloc(big ? WT_BIG : WT_SMALL);
  float* tab = (float*)alloc(TAB_B);
  f16* h     = (f16*)alloc(H_B);
  char* act  = alloc(ACT_B);
  // attention-phase overlays inside act:
  f16* qkv    = (f16*)(act);                                    // 33.5 MB
  f16* q_g    = (f16*)(act + (size_t)33554432);                 // 16.8 MB
  f16* k_g    = (f16*)(act + (size_t)33554432 + 16777216);      //  8.4 MB
  f16* v_n    = (f16*)(act + (size_t)33554432 + 16777216 + 8388608);
  f16* vtb    = (f16*)(act + (size_t)33554432 + 16777216 + 2 * 8388608);
  f16* ctx    = (f16*)(act + (size_t)33554432 + 16777216 + 3 * 8388608);
  f16* attn_o = (f16*)(act);            // reuse qkv slot (dead after norm_rope)
  // ffw-phase overlays:
  f16* gbuf = (f16*)(act);              // 83.9 MB spans whole act region
  f16* ffw  = h;                        // h dead after it's consumed as GEMM A
  f16* wuT  = wT + (size_t)10240 * 2560;  // big path only
  (void)in_sizes; (void)n_in; (void)out_size;

  dim3 tb(32, 8);
  rope_table_k<<<1024, 256, 0, stream>>>(tab);

  // ---- attention path ----
  rmsnorm_f32_f16<<<4096, 256, 0, stream>>>(x, pre_attn, h);
  // wq|wk|wv -> wT as [4096][2560] (q rows 0-2047, k 2048-3071, v 3072-4095)
  transpose_w<<<dim3(2048 / 32, 2560 / 32), tb, 0, stream>>>(wq, wT, 2560, 2048);
  transpose_w<<<dim3(1024 / 32, 2560 / 32), tb, 0, stream>>>(wk, wT + (size_t)2048 * 2560, 2560, 1024);
  transpose_w<<<dim3(1024 / 32, 2560 / 32), tb, 0, stream>>>(wv, wT + (size_t)3072 * 2560, 2560, 1024);
  gemm256<0><<<dim3(4096 / 256, 4096 / 256), 512, 131072, stream>>>(h, wT, qkv, nullptr, 4096, 4096, 2560);
  norm_rope_k<<<4096, 256, 0, stream>>>(qkv, positions, q_scale, k_scale, tab, q_g, k_g, v_n);
  transpose_v_k<<<dim3(2048 / 32, 256 / 32, 8), tb, 0, stream>>>(v_n, vtb);
  flash_attn_k<<<dim3(32, 8, 2), 256, 0, stream>>>(q_g, k_g, vtb, ctx);
  transpose_w<<<dim3(2560 / 32, 2048 / 32), tb, 0, stream>>>(wo, wT, 2048, 2560);
  gemm256<0><<<dim3(2560 / 256, 4096 / 256), 512, 131072, stream>>>(ctx, wT, attn_o, nullptr, 4096, 2560, 2048);
  residual_rmsnorm<<<4096, 256, 0, stream>>>(x, attn_o, post_attn, out);

  // ---- ffw path ----
  rmsnorm_f32_f16<<<4096, 256, 0, stream>>>(out, pre_ffw, h);
  if (big) {
    // fused gate+up: BK=32, 64KB LDS, 2 blocks/CU; grid 80x16 = 1280 blocks
    transpose_w<<<dim3(10240 / 32, 2560 / 32), tb, 0, stream>>>(w_gate, wT, 2560, 10240);
    transpose_w<<<dim3(10240 / 32, 2560 / 32), tb, 0, stream>>>(w_up, wuT, 2560, 10240);
    gemm_fused32<<<dim3(80, 16), 512, 65536, stream>>>(h, wT, gbuf, wuT, 4096, 10240, 2560);
  } else {
    transpose_w<<<dim3(10240 / 32, 2560 / 32), tb, 0, stream>>>(w_gate, wT, 2560, 10240);
    gemm256<1><<<dim3(10240 / 256, 4096 / 256), 512, 131072, stream>>>(h, wT, gbuf, nullptr, 4096, 10240, 2560);
    transpose_w<<<dim3(10240 / 32, 2560 / 32), tb, 0, stream>>>(w_up, wT, 2560, 10240);
    gemm256<2><<<dim3(10240 / 256, 4096 / 256), 512, 131072, stream>>>(h, wT, gbuf, gbuf, 4096, 10240, 2560);
  }
  transpose_w<<<dim3(2560 / 32, 10240 / 32), tb, 0, stream>>>(w_down, wT, 10240, 2560);
  gemm256<0><<<dim3(2560 / 256, 4096 / 256), 512, 131072, stream>>>(gbuf, wT, ffw, nullptr, 4096, 2560, 10240);
  residual_rmsnorm<<<4096, 256, 0, stream>>>(out, ffw, post_ffw, out);
}

// Round 7
// 1154.425 us; speedup vs baseline: 5.2845x; 5.2845x over previous
//
#include <hip/hip_runtime.h>
#include <math.h>

#define DEV __device__ __forceinline__

typedef _Float16 f16;
typedef _Float16 f16x8 __attribute__((ext_vector_type(8)));
typedef _Float16 f16x4 __attribute__((ext_vector_type(4)));
typedef float f32x4 __attribute__((ext_vector_type(4)));

DEV void gload_lds16(const void* g, void* l) {
  __builtin_amdgcn_global_load_lds(
      (const __attribute__((address_space(1))) void*)g,
      (__attribute__((address_space(3))) void*)l, 16, 0, 0);
}

// ---------------------------------------------------------------------------
// Weight transpose + f32->f16: src [R][C] f32 -> dst [C][R] f16.
// 64x64 tiles, 256 threads: float4 reads (256B/row), f16x8 writes (128B rows),
// LDS aliasing <=2-way (free). grid (C/64, R/64). R,C % 64 == 0.
__global__ __launch_bounds__(256) void transpose_w64(
    const float* __restrict__ src, f16* __restrict__ dst, int R, int C) {
  __shared__ float tile[64][65];
  const int r0 = blockIdx.y * 64, c0 = blockIdx.x * 64;
  const int tid = threadIdx.x;
  const int rr = tid >> 4;         // 0..15
  const int rc = (tid & 15) * 4;   // col chunk
#pragma unroll
  for (int p = 0; p < 4; ++p) {
    int r = p * 16 + rr;
    float4 v = *(const float4*)(src + (size_t)(r0 + r) * C + c0 + rc);
    tile[r][rc] = v.x; tile[r][rc + 1] = v.y;
    tile[r][rc + 2] = v.z; tile[r][rc + 3] = v.w;
  }
  __syncthreads();
  const int wc = tid >> 3;         // 0..31
  const int wk = (tid & 7) * 8;    // row chunk base
#pragma unroll
  for (int p = 0; p < 2; ++p) {
    int c = p * 32 + wc;
    f16x8 o;
#pragma unroll
    for (int i = 0; i < 8; ++i) o[i] = (f16)tile[wk + i][c];
    *(f16x8*)(dst + (size_t)(c0 + c) * R + r0 + wk) = o;
  }
}

// ---------------------------------------------------------------------------
// RoPE sin/cos table: tab[pos][0..127]=sin, [128..255]=cos. 2048 pos x 128 j
__global__ void rope_table_k(float* __restrict__ tab) {
  int idx = blockIdx.x * 256 + threadIdx.x;  // 1024 blocks -> 262144 = 2048*128
  int pos = idx >> 7, j = idx & 127;
  float ts = powf(10000.0f, (float)j * (1.0f / 128.0f));
  float ang = (float)pos / ts;
  tab[pos * 256 + j] = sinf(ang);
  tab[pos * 256 + 128 + j] = cosf(ang);
}

// ---------------------------------------------------------------------------
// h = rmsnorm(in, scale) -> f16. one block per row, D=2560
__global__ __launch_bounds__(256) void rmsnorm_f32_f16(
    const float* __restrict__ in, const float* __restrict__ scale,
    f16* __restrict__ out) {
  constexpr int D = 2560, N4 = D / 4;
  const int m = blockIdx.x, tid = threadIdx.x;
  const float* row = in + (size_t)m * D;
  float vals[12];
  float ss = 0.f;
#pragma unroll
  for (int it = 0; it < 3; ++it) {
    int c4 = tid + it * 256;
    if (c4 < N4) {
      float4 v = *(const float4*)(row + c4 * 4);
      vals[it * 4 + 0] = v.x; vals[it * 4 + 1] = v.y;
      vals[it * 4 + 2] = v.z; vals[it * 4 + 3] = v.w;
      ss += v.x * v.x + v.y * v.y + v.z * v.z + v.w * v.w;
    }
  }
#pragma unroll
  for (int off = 32; off; off >>= 1) ss += __shfl_xor(ss, off, 64);
  __shared__ float red[4];
  if ((tid & 63) == 0) red[tid >> 6] = ss;
  __syncthreads();
  float rs = rsqrtf((red[0] + red[1] + red[2] + red[3]) * (1.0f / D) + 1e-6f);
#pragma unroll
  for (int it = 0; it < 3; ++it) {
    int c4 = tid + it * 256;
    if (c4 < N4) {
      float4 sc = *(const float4*)(scale + c4 * 4);
      f16x4 o;
      o[0] = (f16)(vals[it * 4 + 0] * rs * sc.x);
      o[1] = (f16)(vals[it * 4 + 1] * rs * sc.y);
      o[2] = (f16)(vals[it * 4 + 2] * rs * sc.z);
      o[3] = (f16)(vals[it * 4 + 3] * rs * sc.w);
      *(f16x4*)(out + (size_t)m * D + c4 * 4) = o;
    }
  }
}

// ---------------------------------------------------------------------------
// out = x + rmsnorm(y0[+y1+y2], scale); optionally h = rmsnorm(out)*scale2 f16.
// One block per row (D=2560). Safe when out aliases x (per-thread RMW).
// y1/y2 nullable (split-K partial sums); h/scale2 nullable.
__global__ __launch_bounds__(256) void residual_rmsnorm3(
    const float* __restrict__ x, const f16* __restrict__ y0,
    const f16* __restrict__ y1, const f16* __restrict__ y2,
    const float* __restrict__ scale, float* __restrict__ out,
    const float* __restrict__ scale2, f16* __restrict__ h) {
  constexpr int D = 2560, N4 = D / 4;
  const int m = blockIdx.x, tid = threadIdx.x;
  const size_t base = (size_t)m * D;
  __shared__ float red[4];
  float yv[12];
  float ss = 0.f;
#pragma unroll
  for (int it = 0; it < 3; ++it) {
    int c4 = tid + it * 256;
    if (c4 < N4) {
      f16x4 u = *(const f16x4*)(y0 + base + c4 * 4);
      float a = (float)u[0], b = (float)u[1], c = (float)u[2], d = (float)u[3];
      if (y1) {
        f16x4 v = *(const f16x4*)(y1 + base + c4 * 4);
        f16x4 w2 = *(const f16x4*)(y2 + base + c4 * 4);
        a += (float)v[0] + (float)w2[0]; b += (float)v[1] + (float)w2[1];
        c += (float)v[2] + (float)w2[2]; d += (float)v[3] + (float)w2[3];
      }
      yv[it * 4 + 0] = a; yv[it * 4 + 1] = b; yv[it * 4 + 2] = c; yv[it * 4 + 3] = d;
      ss += a * a + b * b + c * c + d * d;
    }
  }
#pragma unroll
  for (int off = 32; off; off >>= 1) ss += __shfl_xor(ss, off, 64);
  if ((tid & 63) == 0) red[tid >> 6] = ss;
  __syncthreads();
  float rs = rsqrtf((red[0] + red[1] + red[2] + red[3]) * (1.0f / D) + 1e-6f);
  float ss2 = 0.f;
#pragma unroll
  for (int it = 0; it < 3; ++it) {
    int c4 = tid + it * 256;
    if (c4 < N4) {
      float4 xv = *(const float4*)(x + base + c4 * 4);
      float4 sc = *(const float4*)(scale + c4 * 4);
      float4 o;
      o.x = xv.x + yv[it * 4 + 0] * rs * sc.x;
      o.y = xv.y + yv[it * 4 + 1] * rs * sc.y;
      o.z = xv.z + yv[it * 4 + 2] * rs * sc.z;
      o.w = xv.w + yv[it * 4 + 3] * rs * sc.w;
      *(float4*)(out + base + c4 * 4) = o;
      yv[it * 4 + 0] = o.x; yv[it * 4 + 1] = o.y;
      yv[it * 4 + 2] = o.z; yv[it * 4 + 3] = o.w;
      ss2 += o.x * o.x + o.y * o.y + o.z * o.z + o.w * o.w;
    }
  }
  if (h) {
#pragma unroll
    for (int off = 32; off; off >>= 1) ss2 += __shfl_xor(ss2, off, 64);
    __syncthreads();
    if ((tid & 63) == 0) red[tid >> 6] = ss2;
    __syncthreads();
    float rs2 = rsqrtf((red[0] + red[1] + red[2] + red[3]) * (1.0f / D) + 1e-6f);
#pragma unroll
    for (int it = 0; it < 3; ++it) {
      int c4 = tid + it * 256;
      if (c4 < N4) {
        float4 sc = *(const float4*)(scale2 + c4 * 4);
        f16x4 o;
        o[0] = (f16)(yv[it * 4 + 0] * rs2 * sc.x);
        o[1] = (f16)(yv[it * 4 + 1] * rs2 * sc.y);
        o[2] = (f16)(yv[it * 4 + 2] * rs2 * sc.z);
        o[3] = (f16)(yv[it * 4 + 3] * rs2 * sc.w);
        *(f16x4*)(h + base + c4 * 4) = o;
      }
    }
  }
}

// ---------------------------------------------------------------------------
// Per-head rmsnorm (+RoPE for q,k) on qkv [4096][4096] f16.
// vectors: 0-7 q heads, 8-11 k heads, 12-15 v heads. one block per token.
__global__ __launch_bounds__(256) void norm_rope_k(
    const f16* __restrict__ qkv, const int* __restrict__ positions,
    const float* __restrict__ q_scale, const float* __restrict__ k_scale,
    const float* __restrict__ tab,
    f16* __restrict__ q_g, f16* __restrict__ k_g, f16* __restrict__ v_n) {
  const int m = blockIdx.x;
  const int tid = threadIdx.x, w = tid >> 6, l = tid & 63;
  const int pos = positions[m];
  const float* srow = tab + (size_t)pos * 256;
  const int c0 = l * 4;
  for (int vi = w; vi < 16; vi += 4) {
    f16x4 u = *(const f16x4*)(qkv + (size_t)m * 4096 + vi * 256 + c0);
    float x0 = (float)u[0], x1 = (float)u[1], x2 = (float)u[2], x3 = (float)u[3];
    float ss = x0 * x0 + x1 * x1 + x2 * x2 + x3 * x3;
#pragma unroll
    for (int off = 32; off; off >>= 1) ss += __shfl_xor(ss, off, 64);
    float rs = rsqrtf(ss * (1.0f / 256.0f) + 1e-6f);
    if (vi < 12) {
      const float* sc = (vi < 8) ? q_scale : k_scale;
      float4 s4 = *(const float4*)(sc + c0);
      float n0 = x0 * rs * s4.x, n1 = x1 * rs * s4.y;
      float n2 = x2 * rs * s4.z, n3 = x3 * rs * s4.w;
      float p0 = __shfl_xor(n0, 32, 64), p1 = __shfl_xor(n1, 32, 64);
      float p2 = __shfl_xor(n2, 32, 64), p3 = __shfl_xor(n3, 32, 64);
      int j0 = c0 & 127;
      float4 sn = *(const float4*)(srow + j0);
      float4 cs = *(const float4*)(srow + 128 + j0);
      float sgn = (l < 32) ? -1.0f : 1.0f;
      f16x4 o;
      o[0] = (f16)(n0 * cs.x + sgn * p0 * sn.x);
      o[1] = (f16)(n1 * cs.y + sgn * p1 * sn.y);
      o[2] = (f16)(n2 * cs.z + sgn * p2 * sn.z);
      o[3] = (f16)(n3 * cs.w + sgn * p3 * sn.w);
      if (vi < 8) *(f16x4*)(q_g + (size_t)m * 2048 + vi * 256 + c0) = o;
      else        *(f16x4*)(k_g + (size_t)m * 1024 + (vi - 8) * 256 + c0) = o;
    } else {
      f16x4 o;
      o[0] = (f16)(x0 * rs); o[1] = (f16)(x1 * rs);
      o[2] = (f16)(x2 * rs); o[3] = (f16)(x3 * rs);
      *(f16x4*)(v_n + (size_t)m * 1024 + (vi - 12) * 256 + c0) = o;
    }
  }
}

// v_n [4096][1024] -> vt [B*KV=8][256][2048] (per-(b,kv) transposed)
__global__ void transpose_v_k(const f16* __restrict__ v_n, f16* __restrict__ vt) {
  __shared__ f16 tile[32][33];
  int bkv = blockIdx.z;
  int b = bkv >> 2, kv = bkv & 3;
  int t0 = blockIdx.x * 32, d0 = blockIdx.y * 32;
  int tx = threadIdx.x, ty = threadIdx.y;
#pragma unroll
  for (int j = 0; j < 32; j += 8)
    tile[ty + j][tx] =
        v_n[(size_t)(b * 2048 + t0 + ty + j) * 1024 + kv * 256 + d0 + tx];
  __syncthreads();
#pragma unroll
  for (int j = 0; j < 32; j += 8)
    vt[((size_t)bkv * 256 + d0 + ty + j) * 2048 + t0 + tx] = tile[tx][ty + j];
}

// ---------------------------------------------------------------------------
// 256x256 GEMM, round-2/4 schedule (best measured): 2 barriers per K-tile,
// counted vmcnt(6)/(4)/(0). BK=64, 128KB LDS double-buffer, 1 block/CU,
// 512 threads = 8 waves (2Mx4N). XOR-swizzled via pre-swizzled source.
// Round-locality decode: bm = orig & 15 (M==4096 required at all call sites).
// EPI: 0=store; 1=gelu(exact); 2=mul by aux[idx] (in-place ok);
// 3=fused gate+up (BT=gate^T rows 0-127, aux=up^T rows 128-255; epilogue
//   exchanges gelu(g) via padded f16 LDS, writes gelu(g)*u to 128 C-cols);
// 4=split-K=3: grid 3x blocks; q=orig>>4 -> bn=q%nper, s=q/nper; K-window
//   derived per s from ktn total tiles; s=0 stores to C, s>0 to
//   aux + (s-1)*M*N (f16 partials, summed later by residual_rmsnorm3).
template <int EPI>
__global__ __launch_bounds__(512, 2) void gemm256(
    const f16* __restrict__ A, const f16* __restrict__ BT,
    f16* __restrict__ C, f16* __restrict__ aux, int M, int N, int K,
    int kt0, int ktn) {
  extern __shared__ __align__(16) f16 lds[];  // 131072 B
  const int tid = threadIdx.x;
  const int w = tid >> 6, l = tid & 63;
  const int l15 = l & 15, lk = l >> 4;
  const int wm = w >> 2, wn = w & 3;  // 2 x 4 wave grid

  const int orig = blockIdx.y * gridDim.x + blockIdx.x;
  const int bm = orig & 15;
  int bn, sK = 0;
  if constexpr (EPI == 4) {
    const int nper = (((int)(gridDim.x * gridDim.y)) >> 4) / 3;
    const int q = orig >> 4;
    bn = q % nper; sK = q / nper;
  } else {
    bn = orig >> 4;
  }
  int kt0v, ktnv;
  if constexpr (EPI == 4) {
    const int qt = ktn / 3, r = ktn % 3;
    ktnv = qt + (sK < r ? 1 : 0);
    kt0v = sK * qt + (sK < r ? sK : r);
  } else {
    kt0v = kt0; ktnv = ktn;
  }
  const int NT = ktnv;

  // staging: thread writes 16B chunks at panel rows srow, srow+128.
  // source col pre-swizzled so linear global_load_lds + swizzled ds_read agree.
  const int srow = tid >> 2;
  const int sg = (tid & 3) ^ ((srow >> 1) & 3);
  const f16* pA1 = A + (size_t)(bm * 256 + srow) * K + sg * 8 + kt0v * 64;
  const f16* pA2 = pA1 + (size_t)128 * K;
  const f16* pB1;
  const f16* pB2;
  if constexpr (EPI == 3) {
    pB1 = BT + (size_t)(bn * 128 + srow) * K + sg * 8 + kt0v * 64;
    pB2 = aux + (size_t)(bn * 128 + srow) * K + sg * 8 + kt0v * 64;
  } else {
    pB1 = BT + (size_t)(bn * 256 + srow) * K + sg * 8 + kt0v * 64;
    pB2 = pB1 + (size_t)128 * K;
  }

  auto stage = [&](int op, int kh, int buf, int kt) {
    const int kb = kt * 64 + kh * 32;
    const f16* s1 = (op ? pB1 : pA1) + kb;
    const f16* s2 = (op ? pB2 : pA2) + kb;
    f16* dst = lds + ((buf << 2) + (kh << 1) + op) * 8192 + tid * 8;
    gload_lds16(s1, dst);
    gload_lds16(s2, dst + 4096);
  };

  // frag read offsets: row*32 elts + swizzled 16B slot (constant per thread)
  const int fcol = (lk ^ ((l15 >> 1) & 3)) << 3;
  const int aoff = (wm * 128 + l15) * 32 + fcol;          // A unit base + mi*512
  const int boff = 8192 + (wn * 64 + l15) * 32 + fcol;    // B unit base + ni*512

  f32x4 acc[8][4] = {};

  // prologue: A0(0), B0(0), A1(0), B1(0), A0(1). vmcnt(6) -> first 2 units landed.
  stage(0, 0, 0, 0);
  stage(1, 0, 0, 0);
  stage(0, 1, 0, 0);
  stage(1, 1, 0, 0);
  if (NT > 1) stage(0, 0, 1, 1);
  asm volatile("s_waitcnt vmcnt(6)" ::: "memory");
  __builtin_amdgcn_s_barrier();
  asm volatile("" ::: "memory");

  for (int t = 0; t < NT; ++t) {
    const int buf = t & 1, nbuf = buf ^ 1;
    const f16* lb0 = lds + buf * 32768;   // kh0 units
    const f16* lb1 = lb0 + 16384;         // kh1 units
    {
      // ---- pair 1: kh0 (A lo+hi, B; 32 MFMA) ----
      f16x8 a1[4], b[4], a2[4];
#pragma unroll
      for (int i = 0; i < 4; ++i) a1[i] = *(const f16x8*)(lb0 + aoff + i * 512);
#pragma unroll
      for (int i = 0; i < 4; ++i) b[i] = *(const f16x8*)(lb0 + boff + i * 512);
#pragma unroll
      for (int i = 0; i < 4; ++i) a2[i] = *(const f16x8*)(lb0 + aoff + (4 + i) * 512);
      if (t + 1 < NT) stage(1, 0, nbuf, t + 1);
      __builtin_amdgcn_s_setprio(1);
#pragma unroll
      for (int mi = 0; mi < 4; ++mi)
#pragma unroll
        for (int ni = 0; ni < 4; ++ni)
          acc[mi][ni] = __builtin_amdgcn_mfma_f32_16x16x32_f16(a1[mi], b[ni], acc[mi][ni], 0, 0, 0);
      __builtin_amdgcn_s_setprio(0);
      if (t + 1 < NT) stage(0, 1, nbuf, t + 1);
      __builtin_amdgcn_s_setprio(1);
#pragma unroll
      for (int mi = 0; mi < 4; ++mi)
#pragma unroll
        for (int ni = 0; ni < 4; ++ni)
          acc[4 + mi][ni] = __builtin_amdgcn_mfma_f32_16x16x32_f16(a2[mi], b[ni], acc[4 + mi][ni], 0, 0, 0);
      __builtin_amdgcn_s_setprio(0);
    }
    // guard: A1(t),B1(t) staged for pair 2 (exact count at tail)
    if (t + 1 < NT) asm volatile("s_waitcnt vmcnt(6)" ::: "memory");
    else            asm volatile("s_waitcnt vmcnt(0)" ::: "memory");
    __builtin_amdgcn_s_barrier();
    asm volatile("" ::: "memory");
    {
      // ---- pair 2: kh1 ----
      f16x8 a1[4], b[4], a2[4];
#pragma unroll
      for (int i = 0; i < 4; ++i) a1[i] = *(const f16x8*)(lb1 + aoff + i * 512);
#pragma unroll
      for (int i = 0; i < 4; ++i) b[i] = *(const f16x8*)(lb1 + boff + i * 512);
#pragma unroll
      for (int i = 0; i < 4; ++i) a2[i] = *(const f16x8*)(lb1 + aoff + (4 + i) * 512);
      if (t + 1 < NT) stage(1, 1, nbuf, t + 1);
      __builtin_amdgcn_s_setprio(1);
#pragma unroll
      for (int mi = 0; mi < 4; ++mi)
#pragma unroll
        for (int ni = 0; ni < 4; ++ni)
          acc[mi][ni] = __builtin_amdgcn_mfma_f32_16x16x32_f16(a1[mi], b[ni], acc[mi][ni], 0, 0, 0);
      __builtin_amdgcn_s_setprio(0);
      if (t + 2 < NT) stage(0, 0, buf, t + 2);  // A-kh0(t) dead since pair-1 reads
      __builtin_amdgcn_s_setprio(1);
#pragma unroll
      for (int mi = 0; mi < 4; ++mi)
#pragma unroll
        for (int ni = 0; ni < 4; ++ni)
          acc[4 + mi][ni] = __builtin_amdgcn_mfma_f32_16x16x32_f16(a2[mi], b[ni], acc[4 + mi][ni], 0, 0, 0);
      __builtin_amdgcn_s_setprio(0);
    }
    // guard: A0(t+1),B0(t+1) staged for next pair-1 (exact count at tail)
    if (t + 2 < NT)      asm volatile("s_waitcnt vmcnt(6)" ::: "memory");
    else if (t + 1 < NT) asm volatile("s_waitcnt vmcnt(4)" ::: "memory");
    else                 asm volatile("s_waitcnt vmcnt(0)" ::: "memory");
    __builtin_amdgcn_s_barrier();
    asm volatile("" ::: "memory");
  }

  // epilogue: C/D map col=l15, row=lk*4+i (m89-verified)
  if constexpr (EPI == 3) {
    // gate waves (wn<2) write gelu(g) to padded f16 LDS; up waves multiply.
    constexpr int XP = 136;  // row pad: stride 272 B -> <=2-way bank aliasing
    __syncthreads();
    f16* xls = lds;  // [256][136] f16 = 69.6 KB
    if (wn < 2) {
#pragma unroll
      for (int mi = 0; mi < 8; ++mi)
#pragma unroll
        for (int ni = 0; ni < 4; ++ni)
#pragma unroll
          for (int i = 0; i < 4; ++i) {
            int row = wm * 128 + mi * 16 + lk * 4 + i;
            int col = wn * 64 + ni * 16 + l15;
            float v = acc[mi][ni][i];
            v = 0.5f * v * (1.0f + erff(v * 0.70710678118654752f));
            xls[row * XP + col] = (f16)v;
          }
    }
    __syncthreads();
    if (wn >= 2) {
#pragma unroll
      for (int mi = 0; mi < 8; ++mi)
#pragma unroll
        for (int ni = 0; ni < 4; ++ni)
#pragma unroll
          for (int i = 0; i < 4; ++i) {
            int row = wm * 128 + mi * 16 + lk * 4 + i;
            int colg = (wn - 2) * 64 + ni * 16 + l15;
            float g = (float)xls[row * XP + colg];
            float v = g * acc[mi][ni][i];
            C[(size_t)(bm * 256 + row) * N + bn * 128 + colg] = (f16)v;
          }
    }
  } else {
    f16* Co = C;
    if constexpr (EPI == 4) {
      if (sK) Co = aux + (size_t)(sK - 1) * ((size_t)M * N);
    }
#pragma unroll
    for (int mi = 0; mi < 8; ++mi) {
#pragma unroll
      for (int ni = 0; ni < 4; ++ni) {
#pragma unroll
        for (int i = 0; i < 4; ++i) {
          int row = bm * 256 + wm * 128 + mi * 16 + lk * 4 + i;
          int col = bn * 256 + wn * 64 + ni * 16 + l15;
          size_t idx = (size_t)row * N + col;
          float v = acc[mi][ni][i];
          if constexpr (EPI == 1) {
            v = 0.5f * v * (1.0f + erff(v * 0.70710678118654752f));
          } else if constexpr (EPI == 2) {
            v *= (float)aux[idx];
          }
          Co[idx] = (f16)v;
        }
      }
    }
  }
}

// ---------------------------------------------------------------------------
// Flash attention, sliding window 1024, GQA rep=2.
// grid (L/64, H, B), block 256 (4 waves, 16 q-rows each). KV tile = 32.
__global__ __launch_bounds__(256) void flash_attn_k(
    const f16* __restrict__ q_g, const f16* __restrict__ k_g,
    const f16* __restrict__ vt, f16* __restrict__ ctx) {
  constexpr int KP = 264, VP = 40, PP = 40;
  __shared__ f16 Ks[32 * KP];
  __shared__ f16 Vs[256 * VP];
  __shared__ f16 Ps[4][16 * PP];
  const int qt = blockIdx.x, h = blockIdx.y, b = blockIdx.z;
  const int tid = threadIdx.x, w = tid >> 6, l = tid & 63;
  const int l15 = l & 15, lk = l >> 4;
  const int kv = h >> 1;

  f16x8 aq[8];
  const int qrow = qt * 64 + w * 16 + l15;
  const f16* qp = q_g + (size_t)(b * 2048 + qrow) * 2048 + h * 256 + lk * 8;
#pragma unroll
  for (int kc = 0; kc < 8; ++kc) aq[kc] = *(const f16x8*)(qp + kc * 32);

  f32x4 o[16] = {};
  float mrow[4] = {-1e30f, -1e30f, -1e30f, -1e30f};
  float lrow[4] = {0.f, 0.f, 0.f, 0.f};

  int kt_lo = 2 * qt - 32; if (kt_lo < 0) kt_lo = 0;
  const int kt_hi = 2 * qt + 1;
  const int iqb = qt * 64 + w * 16 + lk * 4;

  for (int kt = kt_lo; kt <= kt_hi; ++kt) {
    __syncthreads();
#pragma unroll
    for (int it = 0; it < 4; ++it) {
      int ch = tid + it * 256;
      int jl = ch >> 5, kcc = (ch & 31) * 8;
      *(f16x8*)&Ks[jl * KP + kcc] = *(const f16x8*)(
          k_g + (size_t)(b * 2048 + kt * 32 + jl) * 1024 + kv * 256 + kcc);
      int d = ch >> 2, tc = (ch & 3) * 8;
      *(f16x8*)&Vs[d * VP + tc] = *(const f16x8*)(
          vt + ((size_t)(b * 4 + kv) * 256 + d) * 2048 + kt * 32 + tc);
    }
    __syncthreads();
    // S = Q K^T  (16q x 32k per wave)
    f32x4 s[2] = {};
#pragma unroll
    for (int ct = 0; ct < 2; ++ct)
#pragma unroll
      for (int kc = 0; kc < 8; ++kc) {
        f16x8 bk = *(const f16x8*)&Ks[(ct * 16 + l15) * KP + kc * 32 + lk * 8];
        s[ct] = __builtin_amdgcn_mfma_f32_16x16x32_f16(aq[kc], bk, s[ct], 0, 0, 0);
      }
    // mask + online softmax
    float pm[4] = {-1e30f, -1e30f, -1e30f, -1e30f};
#pragma unroll
    for (int ct = 0; ct < 2; ++ct)
#pragma unroll
      for (int i = 0; i < 4; ++i) {
        int iq = iqb + i;
        int j = kt * 32 + ct * 16 + l15;
        bool valid = (j <= iq) && (j > iq - 1024);
        float sv = valid ? s[ct][i] : -1e30f;
        s[ct][i] = sv;
        pm[i] = fmaxf(pm[i], sv);
      }
#pragma unroll
    for (int i = 0; i < 4; ++i)
#pragma unroll
      for (int off = 1; off < 16; off <<= 1)
        pm[i] = fmaxf(pm[i], __shfl_xor(pm[i], off, 64));
    float corr[4], rsum[4];
#pragma unroll
    for (int i = 0; i < 4; ++i) {
      float mn = fmaxf(mrow[i], pm[i]);
      corr[i] = __expf(mrow[i] - mn);
      mrow[i] = mn;
      rsum[i] = 0.f;
    }
#pragma unroll
    for (int ct = 0; ct < 2; ++ct)
#pragma unroll
      for (int i = 0; i < 4; ++i) {
        float p = (s[ct][i] > -1e29f) ? __expf(s[ct][i] - mrow[i]) : 0.f;
        s[ct][i] = p;
        rsum[i] += p;
      }
#pragma unroll
    for (int i = 0; i < 4; ++i) {
#pragma unroll
      for (int off = 1; off < 16; off <<= 1) rsum[i] += __shfl_xor(rsum[i], off, 64);
      lrow[i] = lrow[i] * corr[i] + rsum[i];
    }
#pragma unroll
    for (int dt = 0; dt < 16; ++dt)
#pragma unroll
      for (int i = 0; i < 4; ++i) o[dt][i] *= corr[i];
    // P -> LDS (f16)
#pragma unroll
    for (int ct = 0; ct < 2; ++ct)
#pragma unroll
      for (int i = 0; i < 4; ++i)
        Ps[w][(lk * 4 + i) * PP + ct * 16 + l15] = (f16)s[ct][i];
    __syncthreads();
    // O += P V
    f16x8 pa = *(const f16x8*)&Ps[w][l15 * PP + lk * 8];
#pragma unroll
    for (int dt = 0; dt < 16; ++dt) {
      f16x8 bv = *(const f16x8*)&Vs[(dt * 16 + l15) * VP + lk * 8];
      o[dt] = __builtin_amdgcn_mfma_f32_16x16x32_f16(pa, bv, o[dt], 0, 0, 0);
    }
  }
  float inv[4];
#pragma unroll
  for (int i = 0; i < 4; ++i) inv[i] = 1.0f / lrow[i];
  f16* op = ctx + (size_t)(b * 2048 + qt * 64 + w * 16 + lk * 4) * 2048 + h * 256 + l15;
#pragma unroll
  for (int dt = 0; dt < 16; ++dt)
#pragma unroll
    for (int i = 0; i < 4; ++i)
      op[(size_t)i * 2048 + dt * 16] = (f16)(o[dt][i] * inv[i]);
}

// ---------------------------------------------------------------------------
extern "C" void kernel_launch(void* const* d_in, const int* in_sizes, int n_in,
                              void* d_out, int out_size, void* d_ws, size_t ws_size,
                              hipStream_t stream) {
  const float* x = (const float*)d_in[0];
  const int* positions = (const int*)d_in[1];
  const float* wq = (const float*)d_in[2];
  const float* wk = (const float*)d_in[3];
  const float* wv = (const float*)d_in[4];
  const float* wo = (const float*)d_in[5];
  const float* q_scale = (const float*)d_in[6];
  const float* k_scale = (const float*)d_in[7];
  const float* pre_attn = (const float*)d_in[8];
  const float* post_attn = (const float*)d_in[9];
  const float* pre_ffw = (const float*)d_in[10];
  const float* post_ffw = (const float*)d_in[11];
  const float* w_gate = (const float*)d_in[12];
  const float* w_up = (const float*)d_in[13];
  const float* w_down = (const float*)d_in[14];
  float* out = (float*)d_out;

  // one-time: allow 128KB dynamic LDS on the GEMMs
  static bool s_attr = []() {
    hipFuncSetAttribute(reinterpret_cast<const void*>(&gemm256<0>),
                        hipFuncAttributeMaxDynamicSharedMemorySize, 131072);
    hipFuncSetAttribute(reinterpret_cast<const void*>(&gemm256<1>),
                        hipFuncAttributeMaxDynamicSharedMemorySize, 131072);
    hipFuncSetAttribute(reinterpret_cast<const void*>(&gemm256<2>),
                        hipFuncAttributeMaxDynamicSharedMemorySize, 131072);
    hipFuncSetAttribute(reinterpret_cast<const void*>(&gemm256<3>),
                        hipFuncAttributeMaxDynamicSharedMemorySize, 131072);
    hipFuncSetAttribute(reinterpret_cast<const void*>(&gemm256<4>),
                        hipFuncAttributeMaxDynamicSharedMemorySize, 131072);
    return true;
  }();
  (void)s_attr;

  // ---- workspace layout ----
  const size_t WT_BIG   = (size_t)20480 * 2560 * 2;  // gate^T + up^T resident
  const size_t WT_SMALL = (size_t)10240 * 2560 * 2;
  const size_t TAB_B = (size_t)2048 * 256 * 4;
  const size_t H_B   = (size_t)4096 * 2560 * 2;
  const size_t ACT_B = (size_t)92280832;
  auto aln = [](size_t v) { return (v + 255) & ~(size_t)255; };
  const bool big = ws_size >= aln(WT_BIG) + aln(TAB_B) + aln(H_B) + aln(ACT_B);

  char* ws = (char*)d_ws;
  size_t off = 0;
  auto alloc = [&](size_t bytes) {
    char* p = ws + off;
    off += (bytes + 255) & ~(size_t)255;
    return p;
  };
  f16* wT    = (f16*)alloc(big ? WT_BIG : WT_SMALL);
  float* tab = (float*)alloc(TAB_B);
  f16* h     = (f16*)alloc(H_B);
  char* act  = alloc(ACT_B);
  // attention-phase overlays inside act:
  f16* qkv    = (f16*)(act);                                    // 33.5 MB
  f16* q_g    = (f16*)(act + (size_t)33554432);                 // 16.8 MB
  f16* k_g    = (f16*)(act + (size_t)33554432 + 16777216);      //  8.4 MB
  f16* v_n    = (f16*)(act + (size_t)33554432 + 16777216 + 8388608);
  f16* vtb    = (f16*)(act + (size_t)33554432 + 16777216 + 2 * 8388608);
  f16* ctx    = (f16*)(act + (size_t)33554432 + 16777216 + 3 * 8388608);
  f16* attn_o = (f16*)(act);            // reuse qkv slot (dead after norm_rope)
  // ffw-phase overlays:
  f16* gbuf = (f16*)(act);              // 83.9 MB spans whole act region
  f16* ffw  = h;                        // h dead after fused gate+up consumes it
  f16* wuT  = wT + (size_t)10240 * 2560;        // big: up^T / attn partials / down^T
  f16* ap1  = wuT;                              // attn-out partials (2x 21MB)
  f16* fp1  = wT;                               // down partials (2x 21MB, gate^T dead)
  (void)in_sizes; (void)n_in; (void)out_size;

  rope_table_k<<<1024, 256, 0, stream>>>(tab);

  // ---- attention path ----
  rmsnorm_f32_f16<<<4096, 256, 0, stream>>>(x, pre_attn, h);
  // wq|wk|wv -> wT as [4096][2560] (q rows 0-2047, k 2048-3071, v 3072-4095)
  transpose_w64<<<dim3(2048 / 64, 2560 / 64), 256, 0, stream>>>(wq, wT, 2560, 2048);
  transpose_w64<<<dim3(1024 / 64, 2560 / 64), 256, 0, stream>>>(wk, wT + (size_t)2048 * 2560, 2560, 1024);
  transpose_w64<<<dim3(1024 / 64, 2560 / 64), 256, 0, stream>>>(wv, wT + (size_t)3072 * 2560, 2560, 1024);
  gemm256<0><<<dim3(16, 16), 512, 131072, stream>>>(h, wT, qkv, nullptr, 4096, 4096, 2560, 0, 40);
  norm_rope_k<<<4096, 256, 0, stream>>>(qkv, positions, q_scale, k_scale, tab, q_g, k_g, v_n);
  transpose_v_k<<<dim3(2048 / 32, 256 / 32, 8), dim3(32, 8), 0, stream>>>(v_n, vtb);
  flash_attn_k<<<dim3(32, 8, 2), 256, 0, stream>>>(q_g, k_g, vtb, ctx);
  transpose_w64<<<dim3(2560 / 64, 2048 / 64), 256, 0, stream>>>(wo, wT, 2048, 2560);
  if (big) {
    // split-K=3: 480 blocks (~94% CU fill); partials ap1, ap1+M*N
    gemm256<4><<<dim3(30, 16), 512, 131072, stream>>>(ctx, wT, attn_o, ap1, 4096, 2560, 2048, 0, 32);
    residual_rmsnorm3<<<4096, 256, 0, stream>>>(x, attn_o, ap1, ap1 + (size_t)4096 * 2560,
                                                post_attn, out, pre_ffw, h);
  } else {
    gemm256<0><<<dim3(10, 16), 512, 131072, stream>>>(ctx, wT, attn_o, nullptr, 4096, 2560, 2048, 0, 32);
    residual_rmsnorm3<<<4096, 256, 0, stream>>>(x, attn_o, nullptr, nullptr,
                                                post_attn, out, pre_ffw, h);
  }

  // ---- ffw path (pre-ffw rmsnorm already fused into residual above) ----
  if (big) {
    // fused gate+up: grid 80x16 = 1280 blocks = 5.0 rounds, 100% fill
    transpose_w64<<<dim3(10240 / 64, 2560 / 64), 256, 0, stream>>>(w_gate, wT, 2560, 10240);
    transpose_w64<<<dim3(10240 / 64, 2560 / 64), 256, 0, stream>>>(w_up, wuT, 2560, 10240);
    gemm256<3><<<dim3(80, 16), 512, 131072, stream>>>(h, wT, gbuf, wuT, 4096, 10240, 2560, 0, 40);
    // down^T -> wuT (up^T dead); split-K=3 down, partials fp1, fp1+M*N (gate^T dead)
    transpose_w64<<<dim3(2560 / 64, 10240 / 64), 256, 0, stream>>>(w_down, wuT, 10240, 2560);
    gemm256<4><<<dim3(30, 16), 512, 131072, stream>>>(gbuf, wuT, ffw, fp1, 4096, 2560, 10240, 0, 160);
    residual_rmsnorm3<<<4096, 256, 0, stream>>>(out, ffw, fp1, fp1 + (size_t)4096 * 2560,
                                                post_ffw, out, nullptr, nullptr);
  } else {
    transpose_w64<<<dim3(10240 / 64, 2560 / 64), 256, 0, stream>>>(w_gate, wT, 2560, 10240);
    gemm256<1><<<dim3(40, 16), 512, 131072, stream>>>(h, wT, gbuf, nullptr, 4096, 10240, 2560, 0, 40);
    transpose_w64<<<dim3(10240 / 64, 2560 / 64), 256, 0, stream>>>(w_up, wT, 2560, 10240);
    gemm256<2><<<dim3(40, 16), 512, 131072, stream>>>(h, wT, gbuf, gbuf, 4096, 10240, 2560, 0, 40);
    transpose_w64<<<dim3(2560 / 64, 10240 / 64), 256, 0, stream>>>(w_down, wT, 10240, 2560);
    gemm256<0><<<dim3(10, 16), 512, 131072, stream>>>(gbuf, wT, ffw, nullptr, 4096, 2560, 10240, 0, 160);
    residual_rmsnorm3<<<4096, 256, 0, stream>>>(out, ffw, nullptr, nullptr,
                                                post_ffw, out, nullptr, nullptr);
  }
}

// Round 8
// 1089.271 us; speedup vs baseline: 5.6005x; 1.0598x over previous
//
#include <hip/hip_runtime.h>
#include <math.h>

#define DEV __device__ __forceinline__

typedef _Float16 f16;
typedef _Float16 f16x8 __attribute__((ext_vector_type(8)));
typedef _Float16 f16x4 __attribute__((ext_vector_type(4)));
typedef float f32x4 __attribute__((ext_vector_type(4)));

DEV void gload_lds16(const void* g, void* l) {
  __builtin_amdgcn_global_load_lds(
      (const __attribute__((address_space(1))) void*)g,
      (__attribute__((address_space(3))) void*)l, 16, 0, 0);
}

// ---------------------------------------------------------------------------
// Weight transpose + f32->f16: src [R][C] f32 -> dst [C][R] f16.
// 64x64 tiles, 256 threads. grid (C/64, R/64). R,C % 64 == 0.
__global__ __launch_bounds__(256) void transpose_w64(
    const float* __restrict__ src, f16* __restrict__ dst, int R, int C) {
  __shared__ float tile[64][65];
  const int r0 = blockIdx.y * 64, c0 = blockIdx.x * 64;
  const int tid = threadIdx.x;
  const int rr = tid >> 4;
  const int rc = (tid & 15) * 4;
#pragma unroll
  for (int p = 0; p < 4; ++p) {
    int r = p * 16 + rr;
    float4 v = *(const float4*)(src + (size_t)(r0 + r) * C + c0 + rc);
    tile[r][rc] = v.x; tile[r][rc + 1] = v.y;
    tile[r][rc + 2] = v.z; tile[r][rc + 3] = v.w;
  }
  __syncthreads();
  const int wc = tid >> 3;
  const int wk = (tid & 7) * 8;
#pragma unroll
  for (int p = 0; p < 2; ++p) {
    int c = p * 32 + wc;
    f16x8 o;
#pragma unroll
    for (int i = 0; i < 8; ++i) o[i] = (f16)tile[wk + i][c];
    *(f16x8*)(dst + (size_t)(c0 + c) * R + r0 + wk) = o;
  }
}

// ---------------------------------------------------------------------------
// RoPE sin/cos table: tab[pos][0..127]=sin, [128..255]=cos. 2048 pos x 128 j
__global__ void rope_table_k(float* __restrict__ tab) {
  int idx = blockIdx.x * 256 + threadIdx.x;
  int pos = idx >> 7, j = idx & 127;
  float ts = powf(10000.0f, (float)j * (1.0f / 128.0f));
  float ang = (float)pos / ts;
  tab[pos * 256 + j] = sinf(ang);
  tab[pos * 256 + 128 + j] = cosf(ang);
}

// ---------------------------------------------------------------------------
// h = rmsnorm(in, scale) -> f16. one block per row, D=2560
__global__ __launch_bounds__(256) void rmsnorm_f32_f16(
    const float* __restrict__ in, const float* __restrict__ scale,
    f16* __restrict__ out) {
  constexpr int D = 2560, N4 = D / 4;
  const int m = blockIdx.x, tid = threadIdx.x;
  const float* row = in + (size_t)m * D;
  float vals[12];
  float ss = 0.f;
#pragma unroll
  for (int it = 0; it < 3; ++it) {
    int c4 = tid + it * 256;
    if (c4 < N4) {
      float4 v = *(const float4*)(row + c4 * 4);
      vals[it * 4 + 0] = v.x; vals[it * 4 + 1] = v.y;
      vals[it * 4 + 2] = v.z; vals[it * 4 + 3] = v.w;
      ss += v.x * v.x + v.y * v.y + v.z * v.z + v.w * v.w;
    }
  }
#pragma unroll
  for (int off = 32; off; off >>= 1) ss += __shfl_xor(ss, off, 64);
  __shared__ float red[4];
  if ((tid & 63) == 0) red[tid >> 6] = ss;
  __syncthreads();
  float rs = rsqrtf((red[0] + red[1] + red[2] + red[3]) * (1.0f / D) + 1e-6f);
#pragma unroll
  for (int it = 0; it < 3; ++it) {
    int c4 = tid + it * 256;
    if (c4 < N4) {
      float4 sc = *(const float4*)(scale + c4 * 4);
      f16x4 o;
      o[0] = (f16)(vals[it * 4 + 0] * rs * sc.x);
      o[1] = (f16)(vals[it * 4 + 1] * rs * sc.y);
      o[2] = (f16)(vals[it * 4 + 2] * rs * sc.z);
      o[3] = (f16)(vals[it * 4 + 3] * rs * sc.w);
      *(f16x4*)(out + (size_t)m * D + c4 * 4) = o;
    }
  }
}

// ---------------------------------------------------------------------------
// out = x + rmsnorm(y0[+y1+y2], scale); optionally h = rmsnorm(out)*scale2 f16.
__global__ __launch_bounds__(256) void residual_rmsnorm3(
    const float* __restrict__ x, const f16* __restrict__ y0,
    const f16* __restrict__ y1, const f16* __restrict__ y2,
    const float* __restrict__ scale, float* __restrict__ out,
    const float* __restrict__ scale2, f16* __restrict__ h) {
  constexpr int D = 2560, N4 = D / 4;
  const int m = blockIdx.x, tid = threadIdx.x;
  const size_t base = (size_t)m * D;
  __shared__ float red[4];
  float yv[12];
  float ss = 0.f;
#pragma unroll
  for (int it = 0; it < 3; ++it) {
    int c4 = tid + it * 256;
    if (c4 < N4) {
      f16x4 u = *(const f16x4*)(y0 + base + c4 * 4);
      float a = (float)u[0], b = (float)u[1], c = (float)u[2], d = (float)u[3];
      if (y1) {
        f16x4 v = *(const f16x4*)(y1 + base + c4 * 4);
        f16x4 w2 = *(const f16x4*)(y2 + base + c4 * 4);
        a += (float)v[0] + (float)w2[0]; b += (float)v[1] + (float)w2[1];
        c += (float)v[2] + (float)w2[2]; d += (float)v[3] + (float)w2[3];
      }
      yv[it * 4 + 0] = a; yv[it * 4 + 1] = b; yv[it * 4 + 2] = c; yv[it * 4 + 3] = d;
      ss += a * a + b * b + c * c + d * d;
    }
  }
#pragma unroll
  for (int off = 32; off; off >>= 1) ss += __shfl_xor(ss, off, 64);
  if ((tid & 63) == 0) red[tid >> 6] = ss;
  __syncthreads();
  float rs = rsqrtf((red[0] + red[1] + red[2] + red[3]) * (1.0f / D) + 1e-6f);
  float ss2 = 0.f;
#pragma unroll
  for (int it = 0; it < 3; ++it) {
    int c4 = tid + it * 256;
    if (c4 < N4) {
      float4 xv = *(const float4*)(x + base + c4 * 4);
      float4 sc = *(const float4*)(scale + c4 * 4);
      float4 o;
      o.x = xv.x + yv[it * 4 + 0] * rs * sc.x;
      o.y = xv.y + yv[it * 4 + 1] * rs * sc.y;
      o.z = xv.z + yv[it * 4 + 2] * rs * sc.z;
      o.w = xv.w + yv[it * 4 + 3] * rs * sc.w;
      *(float4*)(out + base + c4 * 4) = o;
      yv[it * 4 + 0] = o.x; yv[it * 4 + 1] = o.y;
      yv[it * 4 + 2] = o.z; yv[it * 4 + 3] = o.w;
      ss2 += o.x * o.x + o.y * o.y + o.z * o.z + o.w * o.w;
    }
  }
  if (h) {
#pragma unroll
    for (int off = 32; off; off >>= 1) ss2 += __shfl_xor(ss2, off, 64);
    __syncthreads();
    if ((tid & 63) == 0) red[tid >> 6] = ss2;
    __syncthreads();
    float rs2 = rsqrtf((red[0] + red[1] + red[2] + red[3]) * (1.0f / D) + 1e-6f);
#pragma unroll
    for (int it = 0; it < 3; ++it) {
      int c4 = tid + it * 256;
      if (c4 < N4) {
        float4 sc = *(const float4*)(scale2 + c4 * 4);
        f16x4 o;
        o[0] = (f16)(yv[it * 4 + 0] * rs2 * sc.x);
        o[1] = (f16)(yv[it * 4 + 1] * rs2 * sc.y);
        o[2] = (f16)(yv[it * 4 + 2] * rs2 * sc.z);
        o[3] = (f16)(yv[it * 4 + 3] * rs2 * sc.w);
        *(f16x4*)(h + base + c4 * 4) = o;
      }
    }
  }
}

// ---------------------------------------------------------------------------
// Per-head rmsnorm (+RoPE for q,k) on qkv [4096][4096] f16.
__global__ __launch_bounds__(256) void norm_rope_k(
    const f16* __restrict__ qkv, const int* __restrict__ positions,
    const float* __restrict__ q_scale, const float* __restrict__ k_scale,
    const float* __restrict__ tab,
    f16* __restrict__ q_g, f16* __restrict__ k_g, f16* __restrict__ v_n) {
  const int m = blockIdx.x;
  const int tid = threadIdx.x, w = tid >> 6, l = tid & 63;
  const int pos = positions[m];
  const float* srow = tab + (size_t)pos * 256;
  const int c0 = l * 4;
  for (int vi = w; vi < 16; vi += 4) {
    f16x4 u = *(const f16x4*)(qkv + (size_t)m * 4096 + vi * 256 + c0);
    float x0 = (float)u[0], x1 = (float)u[1], x2 = (float)u[2], x3 = (float)u[3];
    float ss = x0 * x0 + x1 * x1 + x2 * x2 + x3 * x3;
#pragma unroll
    for (int off = 32; off; off >>= 1) ss += __shfl_xor(ss, off, 64);
    float rs = rsqrtf(ss * (1.0f / 256.0f) + 1e-6f);
    if (vi < 12) {
      const float* sc = (vi < 8) ? q_scale : k_scale;
      float4 s4 = *(const float4*)(sc + c0);
      float n0 = x0 * rs * s4.x, n1 = x1 * rs * s4.y;
      float n2 = x2 * rs * s4.z, n3 = x3 * rs * s4.w;
      float p0 = __shfl_xor(n0, 32, 64), p1 = __shfl_xor(n1, 32, 64);
      float p2 = __shfl_xor(n2, 32, 64), p3 = __shfl_xor(n3, 32, 64);
      int j0 = c0 & 127;
      float4 sn = *(const float4*)(srow + j0);
      float4 cs = *(const float4*)(srow + 128 + j0);
      float sgn = (l < 32) ? -1.0f : 1.0f;
      f16x4 o;
      o[0] = (f16)(n0 * cs.x + sgn * p0 * sn.x);
      o[1] = (f16)(n1 * cs.y + sgn * p1 * sn.y);
      o[2] = (f16)(n2 * cs.z + sgn * p2 * sn.z);
      o[3] = (f16)(n3 * cs.w + sgn * p3 * sn.w);
      if (vi < 8) *(f16x4*)(q_g + (size_t)m * 2048 + vi * 256 + c0) = o;
      else        *(f16x4*)(k_g + (size_t)m * 1024 + (vi - 8) * 256 + c0) = o;
    } else {
      f16x4 o;
      o[0] = (f16)(x0 * rs); o[1] = (f16)(x1 * rs);
      o[2] = (f16)(x2 * rs); o[3] = (f16)(x3 * rs);
      *(f16x4*)(v_n + (size_t)m * 1024 + (vi - 12) * 256 + c0) = o;
    }
  }
}

// v_n [4096][1024] -> vt [B*KV=8][256][2048] (per-(b,kv) transposed)
__global__ void transpose_v_k(const f16* __restrict__ v_n, f16* __restrict__ vt) {
  __shared__ f16 tile[32][33];
  int bkv = blockIdx.z;
  int b = bkv >> 2, kv = bkv & 3;
  int t0 = blockIdx.x * 32, d0 = blockIdx.y * 32;
  int tx = threadIdx.x, ty = threadIdx.y;
#pragma unroll
  for (int j = 0; j < 32; j += 8)
    tile[ty + j][tx] =
        v_n[(size_t)(b * 2048 + t0 + ty + j) * 1024 + kv * 256 + d0 + tx];
  __syncthreads();
#pragma unroll
  for (int j = 0; j < 32; j += 8)
    vt[((size_t)bkv * 256 + d0 + ty + j) * 2048 + t0 + tx] = tile[tx][ty + j];
}

// ---------------------------------------------------------------------------
// 256x256 GEMM, deep-pipeline schedule: BK=32, 3 rotating LDS buffers (96KB),
// prefetch issued 2 tiles ahead -> the per-tile vmcnt(4) waits on loads issued
// ~1.5 tiles (~3500 cyc) earlier (>> 900-cyc HBM latency) = truly free wait.
// One barrier per tile. 512 threads = 8 waves (2Mx4N). Staging unit = 128 rows
// x 32 k of one operand half (8KB, 1 gload/thread); 4 units/tile (A-lo, A-hi,
// B-lo, B-hi). XOR swizzle: LDS[r][c] = global[r][c ^ ((r>>1)&3)] (16B chunks)
// -> frag ds_read_b128 is 2-way bank-aliased (free, m136).
// Round-locality decode: bm = orig & 15 (M==4096 at all call sites).
// kt0/ktn are in 32-k units.
// EPI: 0=store; 1=gelu; 2=mul by aux[idx] (in-place ok);
// 3=fused gate+up, REGISTER-fused: B-lo = gate^T rows (bn*128..+127), B-hi =
//   up^T same rows; wave's ni 0-1 = gate cols, ni 2-3 = up cols; epilogue
//   stores gelu(acc[ni])*acc[ni+2], no LDS exchange. 128 C-cols per block.
// 4=split-K=3 (q=orig>>4 -> bn=q%nper, s=q/nper; s=0 -> C, s>0 ->
//   aux + (s-1)*M*N f16 partials, summed by residual_rmsnorm3).
template <int EPI>
__global__ __launch_bounds__(512, 2) void gemm256(
    const f16* __restrict__ A, const f16* __restrict__ BT,
    f16* __restrict__ C, f16* __restrict__ aux, int M, int N, int K,
    int kt0, int ktn) {
  extern __shared__ __align__(16) f16 lds[];  // 98304 B = 12 units x 4096 f16
  const int tid = threadIdx.x;
  const int w = tid >> 6, l = tid & 63;
  const int l15 = l & 15, lk = l >> 4;
  const int wm = w >> 2, wn = w & 3;  // 2 x 4 wave grid

  const int orig = blockIdx.y * gridDim.x + blockIdx.x;
  const int bm = orig & 15;
  int bn, sK = 0;
  if constexpr (EPI == 4) {
    const int nper = (((int)(gridDim.x * gridDim.y)) >> 4) / 3;
    const int q = orig >> 4;
    bn = q % nper; sK = q / nper;
  } else {
    bn = orig >> 4;
  }
  int kt0v, ktnv;
  if constexpr (EPI == 4) {
    const int qt = ktn / 3, r = ktn % 3;
    ktnv = qt + (sK < r ? 1 : 0);
    kt0v = kt0 + sK * qt + (sK < r ? sK : r);
  } else {
    kt0v = kt0; ktnv = ktn;
  }
  const int NT = ktnv;

  // staging: thread writes one 16B chunk per unit; row srow, swizzled src col.
  const int srow = tid >> 2;
  const int sg = (tid & 3) ^ ((srow >> 1) & 3);
  const f16* src0 = A + (size_t)(bm * 256 + srow) * K + sg * 8 + kt0v * 32;
  const f16* src1 = src0 + (size_t)128 * K;
  const f16* src2;
  const f16* src3;
  if constexpr (EPI == 3) {
    src2 = BT + (size_t)(bn * 128 + srow) * K + sg * 8 + kt0v * 32;   // gate^T
    src3 = aux + (size_t)(bn * 128 + srow) * K + sg * 8 + kt0v * 32;  // up^T
  } else {
    src2 = BT + (size_t)(bn * 256 + srow) * K + sg * 8 + kt0v * 32;
    src3 = src2 + (size_t)128 * K;
  }

  auto stage = [&](int buf, int kt) {
    f16* base = lds + buf * 16384 + tid * 8;
    const int kb = kt * 32;
    gload_lds16(src0 + kb, base);
    gload_lds16(src1 + kb, base + 4096);
    gload_lds16(src2 + kb, base + 8192);
    gload_lds16(src3 + kb, base + 12288);
  };

  // frag read offsets (swizzled 16B chunk; row bits 1-2 == l15 bits 1-2)
  const int fcol = (lk ^ ((l15 >> 1) & 3)) << 3;
  const int aoff = wm * 4096 + l15 * 32 + fcol;  // + buf*16384 + mi*512
  int boff;                                       // EPI!=3: + buf*16384 + ni*512
  if constexpr (EPI != 3) {
    boff = (2 + (wn >> 1)) * 4096 + ((wn & 1) * 64 + l15) * 32 + fcol;
  } else {
    boff = 8192 + (wn * 32 + l15) * 32 + fcol;    // gate unit; up = +4096
  }

  f32x4 acc[8][4] = {};

  // prologue: tiles 0 and 1 staged; vmcnt(4) -> tile 0 landed.
  stage(0, 0);
  if (NT > 1) {
    stage(1, 1);
    asm volatile("s_waitcnt vmcnt(4)" ::: "memory");
  } else {
    asm volatile("s_waitcnt vmcnt(0)" ::: "memory");
  }
  __builtin_amdgcn_s_barrier();
  asm volatile("" ::: "memory");

  int buf = 0;
  for (int t = 0; t < NT; ++t) {
    const int bb = buf * 16384;
    f16x8 a[8], b[4];
#pragma unroll
    for (int i = 0; i < 8; ++i) a[i] = *(const f16x8*)(lds + bb + aoff + i * 512);
    if constexpr (EPI == 3) {
      b[0] = *(const f16x8*)(lds + bb + boff);
      b[1] = *(const f16x8*)(lds + bb + boff + 512);
      b[2] = *(const f16x8*)(lds + bb + boff + 4096);
      b[3] = *(const f16x8*)(lds + bb + boff + 4096 + 512);
    } else {
#pragma unroll
      for (int i = 0; i < 4; ++i) b[i] = *(const f16x8*)(lds + bb + boff + i * 512);
    }
    if (t + 2 < NT) {
      int nb = buf + 2; if (nb >= 3) nb -= 3;
      stage(nb, t + 2);  // overwrites tile t-1's buffer: last read pre-(t-1)-barrier
    }
    __builtin_amdgcn_s_setprio(1);
#pragma unroll
    for (int mi = 0; mi < 8; ++mi)
#pragma unroll
      for (int ni = 0; ni < 4; ++ni)
        acc[mi][ni] = __builtin_amdgcn_mfma_f32_16x16x32_f16(a[mi], b[ni], acc[mi][ni], 0, 0, 0);
    __builtin_amdgcn_s_setprio(0);
    if (t + 1 < NT) {
      // t+1's loads were issued during t-1 (~1.5 tiles ago) -> wait pre-covered
      if (t + 2 < NT) asm volatile("s_waitcnt vmcnt(4)" ::: "memory");
      else            asm volatile("s_waitcnt vmcnt(0)" ::: "memory");
      __builtin_amdgcn_s_barrier();
      asm volatile("" ::: "memory");
    }
    ++buf; if (buf >= 3) buf = 0;
  }

  // epilogue: C/D map col=l15, row=lk*4+i (m89-verified)
  if constexpr (EPI == 3) {
    // register-fused: acc[.][0-1] = gate cols, acc[.][2-3] = up same cols
#pragma unroll
    for (int mi = 0; mi < 8; ++mi)
#pragma unroll
      for (int ni = 0; ni < 2; ++ni)
#pragma unroll
        for (int i = 0; i < 4; ++i) {
          int row = bm * 256 + wm * 128 + mi * 16 + lk * 4 + i;
          int col = bn * 128 + wn * 32 + ni * 16 + l15;
          float g = acc[mi][ni][i];
          g = 0.5f * g * (1.0f + erff(g * 0.70710678118654752f));
          C[(size_t)row * N + col] = (f16)(g * acc[mi][ni + 2][i]);
        }
  } else {
    f16* Co = C;
    if constexpr (EPI == 4) {
      if (sK) Co = aux + (size_t)(sK - 1) * ((size_t)M * N);
    }
#pragma unroll
    for (int mi = 0; mi < 8; ++mi) {
#pragma unroll
      for (int ni = 0; ni < 4; ++ni) {
#pragma unroll
        for (int i = 0; i < 4; ++i) {
          int row = bm * 256 + wm * 128 + mi * 16 + lk * 4 + i;
          int col = bn * 256 + wn * 64 + ni * 16 + l15;
          size_t idx = (size_t)row * N + col;
          float v = acc[mi][ni][i];
          if constexpr (EPI == 1) {
            v = 0.5f * v * (1.0f + erff(v * 0.70710678118654752f));
          } else if constexpr (EPI == 2) {
            v *= (float)aux[idx];
          }
          Co[idx] = (f16)v;
        }
      }
    }
  }
}

// ---------------------------------------------------------------------------
// Flash attention, sliding window 1024, GQA rep=2.
// grid (L/64, H, B), block 256 (4 waves, 16 q-rows each). KV tile = 32.
__global__ __launch_bounds__(256) void flash_attn_k(
    const f16* __restrict__ q_g, const f16* __restrict__ k_g,
    const f16* __restrict__ vt, f16* __restrict__ ctx) {
  constexpr int KP = 264, VP = 40, PP = 40;
  __shared__ f16 Ks[32 * KP];
  __shared__ f16 Vs[256 * VP];
  __shared__ f16 Ps[4][16 * PP];
  const int qt = blockIdx.x, h = blockIdx.y, b = blockIdx.z;
  const int tid = threadIdx.x, w = tid >> 6, l = tid & 63;
  const int l15 = l & 15, lk = l >> 4;
  const int kv = h >> 1;

  f16x8 aq[8];
  const int qrow = qt * 64 + w * 16 + l15;
  const f16* qp = q_g + (size_t)(b * 2048 + qrow) * 2048 + h * 256 + lk * 8;
#pragma unroll
  for (int kc = 0; kc < 8; ++kc) aq[kc] = *(const f16x8*)(qp + kc * 32);

  f32x4 o[16] = {};
  float mrow[4] = {-1e30f, -1e30f, -1e30f, -1e30f};
  float lrow[4] = {0.f, 0.f, 0.f, 0.f};

  int kt_lo = 2 * qt - 32; if (kt_lo < 0) kt_lo = 0;
  const int kt_hi = 2 * qt + 1;
  const int iqb = qt * 64 + w * 16 + lk * 4;

  for (int kt = kt_lo; kt <= kt_hi; ++kt) {
    __syncthreads();
#pragma unroll
    for (int it = 0; it < 4; ++it) {
      int ch = tid + it * 256;
      int jl = ch >> 5, kcc = (ch & 31) * 8;
      *(f16x8*)&Ks[jl * KP + kcc] = *(const f16x8*)(
          k_g + (size_t)(b * 2048 + kt * 32 + jl) * 1024 + kv * 256 + kcc);
      int d = ch >> 2, tc = (ch & 3) * 8;
      *(f16x8*)&Vs[d * VP + tc] = *(const f16x8*)(
          vt + ((size_t)(b * 4 + kv) * 256 + d) * 2048 + kt * 32 + tc);
    }
    __syncthreads();
    f32x4 s[2] = {};
#pragma unroll
    for (int ct = 0; ct < 2; ++ct)
#pragma unroll
      for (int kc = 0; kc < 8; ++kc) {
        f16x8 bk = *(const f16x8*)&Ks[(ct * 16 + l15) * KP + kc * 32 + lk * 8];
        s[ct] = __builtin_amdgcn_mfma_f32_16x16x32_f16(aq[kc], bk, s[ct], 0, 0, 0);
      }
    float pm[4] = {-1e30f, -1e30f, -1e30f, -1e30f};
#pragma unroll
    for (int ct = 0; ct < 2; ++ct)
#pragma unroll
      for (int i = 0; i < 4; ++i) {
        int iq = iqb + i;
        int j = kt * 32 + ct * 16 + l15;
        bool valid = (j <= iq) && (j > iq - 1024);
        float sv = valid ? s[ct][i] : -1e30f;
        s[ct][i] = sv;
        pm[i] = fmaxf(pm[i], sv);
      }
#pragma unroll
    for (int i = 0; i < 4; ++i)
#pragma unroll
      for (int off = 1; off < 16; off <<= 1)
        pm[i] = fmaxf(pm[i], __shfl_xor(pm[i], off, 64));
    float corr[4], rsum[4];
#pragma unroll
    for (int i = 0; i < 4; ++i) {
      float mn = fmaxf(mrow[i], pm[i]);
      corr[i] = __expf(mrow[i] - mn);
      mrow[i] = mn;
      rsum[i] = 0.f;
    }
#pragma unroll
    for (int ct = 0; ct < 2; ++ct)
#pragma unroll
      for (int i = 0; i < 4; ++i) {
        float p = (s[ct][i] > -1e29f) ? __expf(s[ct][i] - mrow[i]) : 0.f;
        s[ct][i] = p;
        rsum[i] += p;
      }
#pragma unroll
    for (int i = 0; i < 4; ++i) {
#pragma unroll
      for (int off = 1; off < 16; off <<= 1) rsum[i] += __shfl_xor(rsum[i], off, 64);
      lrow[i] = lrow[i] * corr[i] + rsum[i];
    }
#pragma unroll
    for (int dt = 0; dt < 16; ++dt)
#pragma unroll
      for (int i = 0; i < 4; ++i) o[dt][i] *= corr[i];
#pragma unroll
    for (int ct = 0; ct < 2; ++ct)
#pragma unroll
      for (int i = 0; i < 4; ++i)
        Ps[w][(lk * 4 + i) * PP + ct * 16 + l15] = (f16)s[ct][i];
    __syncthreads();
    f16x8 pa = *(const f16x8*)&Ps[w][l15 * PP + lk * 8];
#pragma unroll
    for (int dt = 0; dt < 16; ++dt) {
      f16x8 bv = *(const f16x8*)&Vs[(dt * 16 + l15) * VP + lk * 8];
      o[dt] = __builtin_amdgcn_mfma_f32_16x16x32_f16(pa, bv, o[dt], 0, 0, 0);
    }
  }
  float inv[4];
#pragma unroll
  for (int i = 0; i < 4; ++i) inv[i] = 1.0f / lrow[i];
  f16* op = ctx + (size_t)(b * 2048 + qt * 64 + w * 16 + lk * 4) * 2048 + h * 256 + l15;
#pragma unroll
  for (int dt = 0; dt < 16; ++dt)
#pragma unroll
    for (int i = 0; i < 4; ++i)
      op[(size_t)i * 2048 + dt * 16] = (f16)(o[dt][i] * inv[i]);
}

// ---------------------------------------------------------------------------
extern "C" void kernel_launch(void* const* d_in, const int* in_sizes, int n_in,
                              void* d_out, int out_size, void* d_ws, size_t ws_size,
                              hipStream_t stream) {
  const float* x = (const float*)d_in[0];
  const int* positions = (const int*)d_in[1];
  const float* wq = (const float*)d_in[2];
  const float* wk = (const float*)d_in[3];
  const float* wv = (const float*)d_in[4];
  const float* wo = (const float*)d_in[5];
  const float* q_scale = (const float*)d_in[6];
  const float* k_scale = (const float*)d_in[7];
  const float* pre_attn = (const float*)d_in[8];
  const float* post_attn = (const float*)d_in[9];
  const float* pre_ffw = (const float*)d_in[10];
  const float* post_ffw = (const float*)d_in[11];
  const float* w_gate = (const float*)d_in[12];
  const float* w_up = (const float*)d_in[13];
  const float* w_down = (const float*)d_in[14];
  float* out = (float*)d_out;

  static bool s_attr = []() {
    hipFuncSetAttribute(reinterpret_cast<const void*>(&gemm256<0>),
                        hipFuncAttributeMaxDynamicSharedMemorySize, 98304);
    hipFuncSetAttribute(reinterpret_cast<const void*>(&gemm256<1>),
                        hipFuncAttributeMaxDynamicSharedMemorySize, 98304);
    hipFuncSetAttribute(reinterpret_cast<const void*>(&gemm256<2>),
                        hipFuncAttributeMaxDynamicSharedMemorySize, 98304);
    hipFuncSetAttribute(reinterpret_cast<const void*>(&gemm256<3>),
                        hipFuncAttributeMaxDynamicSharedMemorySize, 98304);
    hipFuncSetAttribute(reinterpret_cast<const void*>(&gemm256<4>),
                        hipFuncAttributeMaxDynamicSharedMemorySize, 98304);
    return true;
  }();
  (void)s_attr;

  // ---- workspace layout ----
  const size_t WT_BIG   = (size_t)20480 * 2560 * 2;
  const size_t WT_SMALL = (size_t)10240 * 2560 * 2;
  const size_t TAB_B = (size_t)2048 * 256 * 4;
  const size_t H_B   = (size_t)4096 * 2560 * 2;
  const size_t ACT_B = (size_t)92280832;
  auto aln = [](size_t v) { return (v + 255) & ~(size_t)255; };
  const bool big = ws_size >= aln(WT_BIG) + aln(TAB_B) + aln(H_B) + aln(ACT_B);

  char* ws = (char*)d_ws;
  size_t off = 0;
  auto alloc = [&](size_t bytes) {
    char* p = ws + off;
    off += (bytes + 255) & ~(size_t)255;
    return p;
  };
  f16* wT    = (f16*)alloc(big ? WT_BIG : WT_SMALL);
  float* tab = (float*)alloc(TAB_B);
  f16* h     = (f16*)alloc(H_B);
  char* act  = alloc(ACT_B);
  f16* qkv    = (f16*)(act);
  f16* q_g    = (f16*)(act + (size_t)33554432);
  f16* k_g    = (f16*)(act + (size_t)33554432 + 16777216);
  f16* v_n    = (f16*)(act + (size_t)33554432 + 16777216 + 8388608);
  f16* vtb    = (f16*)(act + (size_t)33554432 + 16777216 + 2 * 8388608);
  f16* ctx    = (f16*)(act + (size_t)33554432 + 16777216 + 3 * 8388608);
  f16* attn_o = (f16*)(act);
  f16* gbuf = (f16*)(act);
  f16* ffw  = h;
  f16* wuT  = wT + (size_t)10240 * 2560;
  f16* ap1  = wuT;
  f16* fp1  = wT;
  (void)in_sizes; (void)n_in; (void)out_size;

  rope_table_k<<<1024, 256, 0, stream>>>(tab);

  // ---- attention path ----
  rmsnorm_f32_f16<<<4096, 256, 0, stream>>>(x, pre_attn, h);
  transpose_w64<<<dim3(2048 / 64, 2560 / 64), 256, 0, stream>>>(wq, wT, 2560, 2048);
  transpose_w64<<<dim3(1024 / 64, 2560 / 64), 256, 0, stream>>>(wk, wT + (size_t)2048 * 2560, 2560, 1024);
  transpose_w64<<<dim3(1024 / 64, 2560 / 64), 256, 0, stream>>>(wv, wT + (size_t)3072 * 2560, 2560, 1024);
  gemm256<0><<<dim3(16, 16), 512, 98304, stream>>>(h, wT, qkv, nullptr, 4096, 4096, 2560, 0, 80);
  norm_rope_k<<<4096, 256, 0, stream>>>(qkv, positions, q_scale, k_scale, tab, q_g, k_g, v_n);
  transpose_v_k<<<dim3(2048 / 32, 256 / 32, 8), dim3(32, 8), 0, stream>>>(v_n, vtb);
  flash_attn_k<<<dim3(32, 8, 2), 256, 0, stream>>>(q_g, k_g, vtb, ctx);
  transpose_w64<<<dim3(2560 / 64, 2048 / 64), 256, 0, stream>>>(wo, wT, 2048, 2560);
  if (big) {
    gemm256<4><<<dim3(30, 16), 512, 98304, stream>>>(ctx, wT, attn_o, ap1, 4096, 2560, 2048, 0, 64);
    residual_rmsnorm3<<<4096, 256, 0, stream>>>(x, attn_o, ap1, ap1 + (size_t)4096 * 2560,
                                                post_attn, out, pre_ffw, h);
  } else {
    gemm256<0><<<dim3(10, 16), 512, 98304, stream>>>(ctx, wT, attn_o, nullptr, 4096, 2560, 2048, 0, 64);
    residual_rmsnorm3<<<4096, 256, 0, stream>>>(x, attn_o, nullptr, nullptr,
                                                post_attn, out, pre_ffw, h);
  }

  // ---- ffw path (pre-ffw rmsnorm fused into residual above) ----
  if (big) {
    transpose_w64<<<dim3(10240 / 64, 2560 / 64), 256, 0, stream>>>(w_gate, wT, 2560, 10240);
    transpose_w64<<<dim3(10240 / 64, 2560 / 64), 256, 0, stream>>>(w_up, wuT, 2560, 10240);
    gemm256<3><<<dim3(80, 16), 512, 98304, stream>>>(h, wT, gbuf, wuT, 4096, 10240, 2560, 0, 80);
    transpose_w64<<<dim3(2560 / 64, 10240 / 64), 256, 0, stream>>>(w_down, wuT, 10240, 2560);
    gemm256<4><<<dim3(30, 16), 512, 98304, stream>>>(gbuf, wuT, ffw, fp1, 4096, 2560, 10240, 0, 320);
    residual_rmsnorm3<<<4096, 256, 0, stream>>>(out, ffw, fp1, fp1 + (size_t)4096 * 2560,
                                                post_ffw, out, nullptr, nullptr);
  } else {
    transpose_w64<<<dim3(10240 / 64, 2560 / 64), 256, 0, stream>>>(w_gate, wT, 2560, 10240);
    gemm256<1><<<dim3(40, 16), 512, 98304, stream>>>(h, wT, gbuf, nullptr, 4096, 10240, 2560, 0, 80);
    transpose_w64<<<dim3(10240 / 64, 2560 / 64), 256, 0, stream>>>(w_up, wT, 2560, 10240);
    gemm256<2><<<dim3(40, 16), 512, 98304, stream>>>(h, wT, gbuf, gbuf, 4096, 10240, 2560, 0, 80);
    transpose_w64<<<dim3(2560 / 64, 10240 / 64), 256, 0, stream>>>(w_down, wT, 10240, 2560);
    gemm256<0><<<dim3(10, 16), 512, 98304, stream>>>(gbuf, wT, ffw, nullptr, 4096, 2560, 10240, 0, 320);
    residual_rmsnorm3<<<4096, 256, 0, stream>>>(out, ffw, nullptr, nullptr,
                                                post_ffw, out, nullptr, nullptr);
  }
}